// Round 9
// baseline (228.151 us; speedup 1.0000x reference)
//
#include <hip/hip_runtime.h>
#include <hip/hip_bf16.h>
#include <cstddef>
#include <cstdint>

// MHA: B=2, N=4096, E=512, H=8, D=64.
// Pipeline: cvt_bf16 -> qkv_proj (768 blocks, 128x128 tile, single-buf LDS,
// 3/CU, XCD remap; plain Vt[B,H,D,N] epilogue) -> flash v14 (= v11 KV-split
// 512-thr/8-wave structure, 86us known-good, + padded merge buffer
// (stride 33/3 dwords: kills the 64-way merge bank conflict) + s_setprio(1)
// around QK and PV MFMA clusters (T5)) -> o_proj (64x64, grid 1024, 4/CU).
// Workspace: qb/kb/vb (Oc aliases qb), Qp/Kp/Vt, wqb..wob. ~52 MB.

typedef __bf16 bf16_t;
typedef __bf16 bf16x8 __attribute__((ext_vector_type(8)));
typedef __bf16 bf16x4 __attribute__((ext_vector_type(4)));
typedef float  f32x4  __attribute__((ext_vector_type(4)));

#define MFMA_BF16 __builtin_amdgcn_mfma_f32_16x16x32_bf16

static __device__ __forceinline__ bf16x8 cvt2(const float4& a, const float4& b) {
  return bf16x8{(bf16_t)a.x,(bf16_t)a.y,(bf16_t)a.z,(bf16_t)a.w,
                (bf16_t)b.x,(bf16_t)b.y,(bf16_t)b.z,(bf16_t)b.w};
}

// pack two f32 -> one 32-bit word of 2 bf16 (lo=a, hi=b), RTNE
static __device__ __forceinline__ uint32_t pk2(float a, float b) {
  uint32_t r;
  asm("v_cvt_pk_bf16_f32 %0, %1, %2" : "=v"(r) : "v"(a), "v"(b));
  return r;
}

// ---------------------------------------------------------------------------
// cvt_bf16: one streaming pass converting all GEMM operands to bf16.
// ---------------------------------------------------------------------------
__global__ void __launch_bounds__(256)
cvt_bf16(const float* __restrict__ q, const float* __restrict__ k,
         const float* __restrict__ v, const float* __restrict__ Wq,
         const float* __restrict__ Wk, const float* __restrict__ Wv,
         const float* __restrict__ Wo,
         bf16_t* __restrict__ qb, bf16_t* __restrict__ kb,
         bf16_t* __restrict__ vb, bf16_t* __restrict__ wq,
         bf16_t* __restrict__ wk, bf16_t* __restrict__ wv,
         bf16_t* __restrict__ wo)
{
  const int CQ = 524288;             // chunks per q/k/v tensor (8 elems each)
  const int CW = 32768;              // chunks per W
  const int TOT = 3 * CQ + 4 * CW;   // 1,703,936
  const int STRIDE = 2048 * 256;
  for (int c = blockIdx.x * 256 + threadIdx.x; c < TOT; c += STRIDE) {
    const float* src; bf16_t* dst; int off;
    if (c < 3 * CQ) {
      const int t = c >> 19;
      const int r = c & (CQ - 1);
      src = (t == 0) ? q : (t == 1) ? k : v;
      dst = (t == 0) ? qb : (t == 1) ? kb : vb;
      off = r << 3;
    } else {
      const int c2 = c - 3 * CQ;
      const int t = c2 >> 15;
      const int r = c2 & (CW - 1);
      src = (t == 0) ? Wq : (t == 1) ? Wk : (t == 2) ? Wv : Wo;
      dst = (t == 0) ? wq : (t == 1) ? wk : (t == 2) ? wv : wo;
      off = r << 3;
    }
    const float4 a = *(const float4*)(src + off);
    const float4 b = *(const float4*)(src + off + 4);
    *(bf16x8*)(dst + off) = cvt2(a, b);
  }
}

// ---------------------------------------------------------------------------
// qkv_proj: all three projections in ONE dispatch, bf16 in (R5 config,
// plain Vt[B,H,D,N] epilogue).
// ---------------------------------------------------------------------------
__global__ void __launch_bounds__(256, 3)
qkv_proj(const bf16_t* __restrict__ qb, const bf16_t* __restrict__ kb,
         const bf16_t* __restrict__ vb,
         const bf16_t* __restrict__ Wqb, const float* __restrict__ bq,
         const bf16_t* __restrict__ Wkb, const float* __restrict__ bk,
         const bf16_t* __restrict__ Wvb, const float* __restrict__ bv,
         bf16_t* __restrict__ Qp, bf16_t* __restrict__ Kp,
         bf16_t* __restrict__ Vt, float qscale)
{
  __shared__ __align__(16) bf16_t S[2 * 128 * 72];   // As | Bs, 36,864 B
  bf16_t* As = S;
  bf16_t* Bs = S + 128 * 72;

  const int l     = blockIdx.x;                  // 0..767
  const int slice = l >> 8;                      // 0=Q, 1=K, 2=V
  const int inner = l & 255;
  const int mtile = ((inner & 7) << 3) | (inner >> 5);  // 0..63, XCD-contig
  const int ntile = (inner >> 3) & 3;                   // 0..3
  const int tid   = threadIdx.x;
  const int w     = tid >> 6;
  const int lane  = tid & 63;
  const int lr    = lane & 15;
  const int quad  = lane >> 4;
  const int wm    = w & 1;
  const int wn    = w >> 1;
  const int xrow  = tid >> 1, xcol = (tid & 1) << 5;  // stage: 128 rows x 64 cols

  const bf16_t* Xb   = (slice == 0) ? qb  : (slice == 1) ? kb  : vb;
  const bf16_t* W    = (slice == 0) ? Wqb : (slice == 1) ? Wkb : Wvb;
  const float*  bias = (slice == 0) ? bq  : (slice == 1) ? bk  : bv;
  const float scale  = (slice == 0) ? qscale : 1.0f;

  float bvv[4];
#pragma unroll
  for (int ci = 0; ci < 4; ++ci) bvv[ci] = bias[ntile * 128 + wn * 64 + ci * 16 + lr];

  f32x4 acc[4][4] = {};
  bf16x8 xa[4], wa[4];

#pragma unroll
  for (int j = 0; j < 4; ++j) {
    xa[j] = *(const bf16x8*)(Xb + (size_t)(mtile * 128 + xrow) * 512 + xcol + j * 8);
    wa[j] = *(const bf16x8*)(W  + (size_t)(ntile * 128 + xrow) * 512 + xcol + j * 8);
  }
#pragma unroll
  for (int j = 0; j < 4; ++j) {
    *(bf16x8*)(&As[xrow * 72 + xcol + j * 8]) = xa[j];
    *(bf16x8*)(&Bs[xrow * 72 + xcol + j * 8]) = wa[j];
  }
  __syncthreads();

  for (int it = 0; it < 8; ++it) {
    if (it != 7) {
      const int k0 = (it + 1) << 6;
#pragma unroll
      for (int j = 0; j < 4; ++j) {
        xa[j] = *(const bf16x8*)(Xb + (size_t)(mtile * 128 + xrow) * 512 + k0 + xcol + j * 8);
        wa[j] = *(const bf16x8*)(W  + (size_t)(ntile * 128 + xrow) * 512 + k0 + xcol + j * 8);
      }
    }
    bf16x8 af[4][2], bfr[4][2];
#pragma unroll
    for (int mi = 0; mi < 4; ++mi)
#pragma unroll
      for (int kh = 0; kh < 2; ++kh)
        af[mi][kh] = *(const bf16x8*)(&As[(wm * 64 + mi * 16 + lr) * 72 + (kh * 4 + quad) * 8]);
#pragma unroll
    for (int ci = 0; ci < 4; ++ci)
#pragma unroll
      for (int kh = 0; kh < 2; ++kh)
        bfr[ci][kh] = *(const bf16x8*)(&Bs[(wn * 64 + ci * 16 + lr) * 72 + (kh * 4 + quad) * 8]);
#pragma unroll
    for (int mi = 0; mi < 4; ++mi)
#pragma unroll
      for (int ci = 0; ci < 4; ++ci) {
        acc[mi][ci] = MFMA_BF16(af[mi][0], bfr[ci][0], acc[mi][ci], 0, 0, 0);
        acc[mi][ci] = MFMA_BF16(af[mi][1], bfr[ci][1], acc[mi][ci], 0, 0, 0);
      }
    __syncthreads();
    if (it != 7) {
#pragma unroll
      for (int j = 0; j < 4; ++j) {
        *(bf16x8*)(&As[xrow * 72 + xcol + j * 8]) = xa[j];
        *(bf16x8*)(&Bs[xrow * 72 + xcol + j * 8]) = wa[j];
      }
      __syncthreads();
    }
  }

  // ---- epilogue: LDS-staged coalesced stores ----
  bf16_t (*Ct)[136] = (bf16_t (*)[136])S;   // 128x136 bf16
  if (slice < 2) {
    bf16_t* outQK = (slice == 0) ? Qp : Kp;
#pragma unroll
    for (int mi = 0; mi < 4; ++mi)
#pragma unroll
      for (int ci = 0; ci < 4; ++ci)
#pragma unroll
        for (int r = 0; r < 4; ++r)
          Ct[wm * 64 + mi * 16 + quad * 4 + r][wn * 64 + ci * 16 + lr] =
              (bf16_t)((acc[mi][ci][r] + bvv[ci]) * scale);
    __syncthreads();
    const int r2 = tid >> 1, half = tid & 1;
    const int gm = mtile * 128 + r2;
    const int b = gm >> 12, n = gm & 4095;
    const int gc0 = ntile * 128 + half * 64;
    const int h = gc0 >> 6;
    bf16_t* dst = outQK + (size_t)((b * 8 + h) * 4096 + n) * 64;
#pragma unroll
    for (int j = 0; j < 8; ++j)
      *(bf16x8*)(dst + j * 8) = *(const bf16x8*)(&Ct[r2][half * 64 + j * 8]);
  } else {
    // V: transpose in LDS -> Vt[B,H,D,N] rows of contiguous n
#pragma unroll
    for (int mi = 0; mi < 4; ++mi)
#pragma unroll
      for (int ci = 0; ci < 4; ++ci)
#pragma unroll
        for (int r = 0; r < 4; ++r)
          Ct[wn * 64 + ci * 16 + lr][wm * 64 + mi * 16 + quad * 4 + r] =
              (bf16_t)(acc[mi][ci][r] + bvv[ci]);
    __syncthreads();
    const int dline = tid >> 1, half = tid & 1;
    const int gc = ntile * 128 + dline;
    const int h = gc >> 6, dd = gc & 63;
    const int b = (mtile * 128) >> 12;
    const int n0 = (mtile * 128) & 4095;
    bf16_t* dst = Vt + (size_t)((b * 8 + h) * 64 + dd) * 4096 + n0 + half * 64;
#pragma unroll
    for (int j = 0; j < 8; ++j)
      *(bf16x8*)(dst + j * 8) = *(const bf16x8*)(&Ct[dline][half * 64 + j * 8]);
  }
}

// ---------------------------------------------------------------------------
// o_proj: final projection, f32 out [B,N,E] (unchanged R5).
// ---------------------------------------------------------------------------
__global__ void __launch_bounds__(256, 4)
o_proj(const bf16_t* __restrict__ Xb, const bf16_t* __restrict__ W,
       const float* __restrict__ bias, float* __restrict__ out)
{
  __shared__ __align__(16) bf16_t As[64 * 72];
  __shared__ __align__(16) bf16_t Bs[64 * 72];
  const int l     = blockIdx.x;
  const int mtile = ((l & 7) << 4) | ((l >> 3) & 15);  // 0..127, XCD-contig
  const int ntile = l >> 7;                            // 0..7
  const int tid   = threadIdx.x;
  const int w     = tid >> 6;
  const int lane  = tid & 63;
  const int lr    = lane & 15;
  const int quad  = lane >> 4;
  const int wm    = w & 1;
  const int wn    = w >> 1;
  const int xrow  = tid >> 2, xcol = (tid & 3) << 4;  // 64 rows x 64 cols

  float bvv[2];
#pragma unroll
  for (int ci = 0; ci < 2; ++ci) bvv[ci] = bias[ntile * 64 + wn * 32 + ci * 16 + lr];

  f32x4 acc[2][2] = {};
  bf16x8 xb[2], wb[2];

#pragma unroll
  for (int j = 0; j < 2; ++j) {
    xb[j] = *(const bf16x8*)(Xb + (size_t)(mtile * 64 + xrow) * 512 + xcol + j * 8);
    wb[j] = *(const bf16x8*)(W  + (size_t)(ntile * 64 + xrow) * 512 + xcol + j * 8);
  }
#pragma unroll
  for (int j = 0; j < 2; ++j) {
    *(bf16x8*)(&As[xrow * 72 + xcol + j * 8]) = xb[j];
    *(bf16x8*)(&Bs[xrow * 72 + xcol + j * 8]) = wb[j];
  }
  __syncthreads();

  for (int it = 0; it < 8; ++it) {
    if (it != 7) {
      const int k0 = (it + 1) << 6;
#pragma unroll
      for (int j = 0; j < 2; ++j) {
        xb[j] = *(const bf16x8*)(Xb + (size_t)(mtile * 64 + xrow) * 512 + k0 + xcol + j * 8);
        wb[j] = *(const bf16x8*)(W  + (size_t)(ntile * 64 + xrow) * 512 + k0 + xcol + j * 8);
      }
    }
    bf16x8 af[2][2], bfr[2][2];
#pragma unroll
    for (int mi = 0; mi < 2; ++mi)
#pragma unroll
      for (int kh = 0; kh < 2; ++kh)
        af[mi][kh] = *(const bf16x8*)(&As[(wm * 32 + mi * 16 + lr) * 72 + (kh * 4 + quad) * 8]);
#pragma unroll
    for (int ci = 0; ci < 2; ++ci)
#pragma unroll
      for (int kh = 0; kh < 2; ++kh)
        bfr[ci][kh] = *(const bf16x8*)(&Bs[(wn * 32 + ci * 16 + lr) * 72 + (kh * 4 + quad) * 8]);
#pragma unroll
    for (int mi = 0; mi < 2; ++mi)
#pragma unroll
      for (int ci = 0; ci < 2; ++ci) {
        acc[mi][ci] = MFMA_BF16(af[mi][0], bfr[ci][0], acc[mi][ci], 0, 0, 0);
        acc[mi][ci] = MFMA_BF16(af[mi][1], bfr[ci][1], acc[mi][ci], 0, 0, 0);
      }
    __syncthreads();
    if (it != 7) {
#pragma unroll
      for (int j = 0; j < 2; ++j) {
        *(bf16x8*)(&As[xrow * 72 + xcol + j * 8]) = xb[j];
        *(bf16x8*)(&Bs[xrow * 72 + xcol + j * 8]) = wb[j];
      }
      __syncthreads();
    }
  }

#pragma unroll
  for (int mi = 0; mi < 2; ++mi) {
    const int gm0 = mtile * 64 + wm * 32 + mi * 16 + quad * 4;
#pragma unroll
    for (int ci = 0; ci < 2; ++ci) {
      const int gc = ntile * 64 + wn * 32 + ci * 16 + lr;
#pragma unroll
      for (int r = 0; r < 4; ++r)
        out[(size_t)(gm0 + r) * 512 + gc] = acc[mi][ci][r] + bvv[ci];
    }
  }
}

// ---------------------------------------------------------------------------
// flash_attn v14: v11 structure (86us known-good): 512 thr = 8 waves,
// grid (16,32), 2 blocks/CU -> 16 waves/CU. Group g = wave>>2: g0 = KV
// chunks 0..31, g1 = 32..63; private dbuf K/V LDS per group (73,728 B).
// 32 q-rows/wave, transposed S, m=0 softmax, in-register P exchange.
// NEW vs v11: (a) merge buffer padded (acc stride 33 dwords, lsum stride 3)
// -> kills the 64-way merge bank conflict; (b) s_setprio(1) around the QK
// and PV MFMA clusters (T5 — wave role diversity from the group split).
// ---------------------------------------------------------------------------
__global__ void __launch_bounds__(512, 2)
flash_attn(const bf16_t* __restrict__ Qp, const bf16_t* __restrict__ Kp,
           const bf16_t* __restrict__ Vt, bf16_t* __restrict__ Oc)
{
  __shared__ __align__(16) bf16_t Klds[2][2][64 * 72];   // [g][buf]
  __shared__ __align__(16) bf16_t Vlds[2][2][64 * 72];

  const int tid  = threadIdx.x;
  const int w    = tid >> 6;               // 0..7
  const int g    = w >> 2;                 // 0..1  (KV half)
  const int wl   = w & 3;                  // 0..3  (q sub-tile)
  const int lane = tid & 63, lr = lane & 15, quad = lane >> 4;
  const int bh   = blockIdx.x;
  const int qt0  = blockIdx.y * 128 + wl * 32;

  const bf16_t* Qh = Qp + (size_t)bh * 4096 * 64;
  const bf16_t* Kh = Kp + (size_t)bh * 4096 * 64;
  const bf16_t* Vh = Vt + (size_t)bh * 64 * 4096;

  const int tg   = tid & 255;              // thread-in-group
  const int srow = tg >> 2;                // 0..63
  const int scol = (tg & 3) << 4;          // 0,16,32,48
  const int kvbase = g << 11;              // g*32 chunks * 64 rows

  bf16x8 qf[2][2];
#pragma unroll
  for (int qi = 0; qi < 2; ++qi)
#pragma unroll
    for (int kh = 0; kh < 2; ++kh)
      qf[qi][kh] = *(const bf16x8*)(Qh + (size_t)(qt0 + qi * 16 + lr) * 64 + kh * 32 + quad * 8);

  bf16x8 kst[2], vst[2];
#pragma unroll
  for (int j = 0; j < 2; ++j) {
    kst[j] = *(const bf16x8*)(Kh + (size_t)(kvbase + srow) * 64 + scol + j * 8);
    vst[j] = *(const bf16x8*)(Vh + (size_t)srow * 4096 + kvbase + scol + j * 8);
  }
#pragma unroll
  for (int j = 0; j < 2; ++j) {
    *(bf16x8*)(&Klds[g][0][srow * 72 + scol + j * 8]) = kst[j];
    *(bf16x8*)(&Vlds[g][0][srow * 72 + scol + j * 8]) = vst[j];
  }
  __syncthreads();

  f32x4 acc[2][4] = {};
  float lsum[2] = {0.f, 0.f};
  const f32x4 zero = {0.f, 0.f, 0.f, 0.f};

  for (int it = 0; it < 32; ++it) {
    const int cur = it & 1, nxt = cur ^ 1;

    if (it != 31) {
      const int kvn = kvbase + ((it + 1) << 6);
#pragma unroll
      for (int j = 0; j < 2; ++j) {
        kst[j] = *(const bf16x8*)(Kh + (size_t)(kvn + srow) * 64 + scol + j * 8);
        vst[j] = *(const bf16x8*)(Vh + (size_t)srow * 4096 + kvn + scol + j * 8);
      }
    }

    bf16x8 kf[4][2];
#pragma unroll
    for (int mt = 0; mt < 4; ++mt)
#pragma unroll
      for (int kh = 0; kh < 2; ++kh)
        kf[mt][kh] = *(const bf16x8*)(&Klds[g][cur][(mt * 16 + lr) * 72 + (kh * 4 + quad) * 8]);
    bf16x8 vf[4][2];
#pragma unroll
    for (int t = 0; t < 4; ++t)
#pragma unroll
      for (int kvh = 0; kvh < 2; ++kvh)
        vf[t][kvh] = *(const bf16x8*)(&Vlds[g][cur][(t * 16 + lr) * 72 + (kvh * 4 + quad) * 8]);

    f32x4 sT[4][2];
    __builtin_amdgcn_s_setprio(1);
#pragma unroll
    for (int mt = 0; mt < 4; ++mt)
#pragma unroll
      for (int qi = 0; qi < 2; ++qi) {
        sT[mt][qi] = MFMA_BF16(kf[mt][0], qf[qi][0], zero, 0, 0, 0);
        sT[mt][qi] = MFMA_BF16(kf[mt][1], qf[qi][1], sT[mt][qi], 0, 0, 0);
      }
    __builtin_amdgcn_s_setprio(0);

    // softmax + in-register P exchange (S^T C-layout -> PV A-frag layout)
    bf16x8 pa[2][2];
#pragma unroll
    for (int qi = 0; qi < 2; ++qi) {
      uint32_t ap[4], bp[4];
#pragma unroll
      for (int mt = 0; mt < 4; ++mt) {
        float p0 = __builtin_amdgcn_exp2f(sT[mt][qi][0]);
        float p1 = __builtin_amdgcn_exp2f(sT[mt][qi][1]);
        float p2 = __builtin_amdgcn_exp2f(sT[mt][qi][2]);
        float p3 = __builtin_amdgcn_exp2f(sT[mt][qi][3]);
        lsum[qi] += (p0 + p1) + (p2 + p3);
        ap[mt] = pk2(p0, p1);
        bp[mt] = pk2(p2, p3);
      }
#pragma unroll
      for (int kvh = 0; kvh < 2; ++kvh) {
        uint32_t xa_ = ap[2 * kvh], ya_ = ap[2 * kvh + 1];
        asm("v_permlane32_swap_b32 %0, %1" : "+v"(xa_), "+v"(ya_));
        asm("v_permlane16_swap_b32 %0, %1" : "+v"(xa_), "+v"(ya_));
        uint32_t xb_ = bp[2 * kvh], yb_ = bp[2 * kvh + 1];
        asm("v_permlane32_swap_b32 %0, %1" : "+v"(xb_), "+v"(yb_));
        asm("v_permlane16_swap_b32 %0, %1" : "+v"(xb_), "+v"(yb_));
        union { uint32_t u[4]; bf16x8 v; } pu;
        pu.u[0] = xa_; pu.u[1] = xb_; pu.u[2] = ya_; pu.u[3] = yb_;
        pa[qi][kvh] = pu.v;
      }
    }

    __builtin_amdgcn_s_setprio(1);
#pragma unroll
    for (int t = 0; t < 4; ++t)
#pragma unroll
      for (int qi = 0; qi < 2; ++qi) {
        acc[qi][t] = MFMA_BF16(pa[qi][0], vf[t][0], acc[qi][t], 0, 0, 0);
        acc[qi][t] = MFMA_BF16(pa[qi][1], vf[t][1], acc[qi][t], 0, 0, 0);
      }
    __builtin_amdgcn_s_setprio(0);

    if (it != 31) {
#pragma unroll
      for (int j = 0; j < 2; ++j) {
        *(bf16x8*)(&Klds[g][nxt][srow * 72 + scol + j * 8]) = kst[j];
        *(bf16x8*)(&Vlds[g][nxt][srow * 72 + scol + j * 8]) = vst[j];
      }
    }
    __syncthreads();
  }

  // intra-wave reduce lsum across quads (each lane ends with its lr-row sum)
#pragma unroll
  for (int qi = 0; qi < 2; ++qi) {
    lsum[qi] += __shfl_xor(lsum[qi], 16);
    lsum[qi] += __shfl_xor(lsum[qi], 32);
  }

  // ---- merge g1 -> g0 via LDS (K staging is dead; padded strides) ----
  // accM: [4 waves][64 lanes][33 f32] = 33,792 B; lsumM: [4][64][3] = 3,072 B
  // -> exactly 36,864 B = the dead Klds region. Stride 33/3 dwords avoids
  // the stride-32 64-way bank conflict of the unpadded layout.
  float* accM  = (float*)&Klds[0][0][0];
  float* lsumM = accM + 4 * 64 * 33;
  const int mslot = (wl * 64 + lane);
  if (g == 1) {
#pragma unroll
    for (int qi = 0; qi < 2; ++qi) {
      lsumM[mslot * 3 + qi] = lsum[qi];
#pragma unroll
      for (int t = 0; t < 4; ++t)
#pragma unroll
        for (int r = 0; r < 4; ++r)
          accM[mslot * 33 + qi * 16 + t * 4 + r] = acc[qi][t][r];
    }
  }
  __syncthreads();
  if (g == 1) return;

#pragma unroll
  for (int qi = 0; qi < 2; ++qi) {
    lsum[qi] += lsumM[mslot * 3 + qi];
#pragma unroll
    for (int t = 0; t < 4; ++t)
#pragma unroll
      for (int r = 0; r < 4; ++r)
        acc[qi][t][r] += accM[mslot * 33 + qi * 16 + t * 4 + r];
  }

  const int b = bh >> 3, h = bh & 7;
  bf16_t* Ob = Oc + (size_t)b * 4096 * 512 + h * 64;
#pragma unroll
  for (int qi = 0; qi < 2; ++qi) {
    float inv[4];
#pragma unroll
    for (int r = 0; r < 4; ++r)
      inv[r] = 1.0f / __shfl(lsum[qi], quad * 4 + r);
#pragma unroll
    for (int t = 0; t < 4; ++t)
#pragma unroll
      for (int r = 0; r < 4; ++r) {
        const int n = qt0 + qi * 16 + quad * 4 + r;
        Ob[(size_t)n * 512 + t * 16 + lr] = (bf16_t)(acc[qi][t][r] * inv[r]);
      }
  }
}

// ---------------------------------------------------------------------------
extern "C" void kernel_launch(void* const* d_in, const int* in_sizes, int n_in,
                              void* d_out, int out_size, void* d_ws, size_t ws_size,
                              hipStream_t stream)
{
  const float* q  = (const float*)d_in[0];
  const float* k  = (const float*)d_in[1];
  const float* v  = (const float*)d_in[2];
  const float* Wq = (const float*)d_in[3];
  const float* bq = (const float*)d_in[4];
  const float* Wk = (const float*)d_in[5];
  const float* bk = (const float*)d_in[6];
  const float* Wv = (const float*)d_in[7];
  const float* bv = (const float*)d_in[8];
  const float* Wo = (const float*)d_in[9];
  const float* bo = (const float*)d_in[10];

  const size_t HEAD_ELEMS = (size_t)2 * 8 * 4096 * 64;  // 4,194,304 (8 MB bf16)
  const size_t W_ELEMS    = (size_t)512 * 512;          // 262,144

  bf16_t* base = (bf16_t*)d_ws;
  bf16_t* qb  = base;                        // [B,N,E] bf16
  bf16_t* kb  = qb + HEAD_ELEMS;
  bf16_t* vb  = kb + HEAD_ELEMS;
  bf16_t* Qp  = vb + HEAD_ELEMS;             // [B,H,N,D], pre-scaled
  bf16_t* Kp  = Qp + HEAD_ELEMS;             // [B,H,N,D]
  bf16_t* Vt  = Kp + HEAD_ELEMS;             // [B,H,D,N]
  bf16_t* wqb = Vt + HEAD_ELEMS;
  bf16_t* wkb = wqb + W_ELEMS;
  bf16_t* wvb = wkb + W_ELEMS;
  bf16_t* wob = wvb + W_ELEMS;
  bf16_t* Oc  = qb;   // aliases qb: dead after qkv_proj, Oc written by flash

  const float qscale = 0.125f * 1.44269504f;  // 1/sqrt(D) * log2(e)

  cvt_bf16<<<dim3(2048), 256, 0, stream>>>(q, k, v, Wq, Wk, Wv, Wo,
                                           qb, kb, vb, wqb, wkb, wvb, wob);
  qkv_proj<<<dim3(768), 256, 0, stream>>>(qb, kb, vb, wqb, bq, wkb, bk,
                                          wvb, bv, Qp, Kp, Vt, qscale);
  flash_attn<<<dim3(16, 32), 512, 0, stream>>>(Qp, Kp, Vt, Oc);
  o_proj<<<dim3(1024), 256, 0, stream>>>(Oc, wob, bo, (float*)d_out);
}

// Round 11
// 221.485 us; speedup vs baseline: 1.0301x; 1.0301x over previous
//
#include <hip/hip_runtime.h>
#include <hip/hip_bf16.h>
#include <cstddef>
#include <cstdint>

// MHA: B=2, N=4096, E=512, H=8, D=64.
// Pipeline: cvt_bf16 -> qkv_proj (768 blocks, 128x128 tile, single-buf LDS,
// 3/CU, XCD remap; plain Vt[B,H,D,N] epilogue) -> flash v16 (= v11 KV-split
// 512-thr/8-wave structure, 86us verified, + padded f32 merge buffer
// (stride 33/3 dwords, verified in R9) — NO setprio (R9: -11us), NO packed
// LDS (R10: unlocalizable correctness failure)) -> o_proj (64x64, grid 1024).
// Workspace: qb/kb/vb (Oc aliases qb), Qp/Kp/Vt, wqb..wob. ~52 MB.

typedef __bf16 bf16_t;
typedef __bf16 bf16x8 __attribute__((ext_vector_type(8)));
typedef __bf16 bf16x4 __attribute__((ext_vector_type(4)));
typedef float  f32x4  __attribute__((ext_vector_type(4)));

#define MFMA_BF16 __builtin_amdgcn_mfma_f32_16x16x32_bf16

static __device__ __forceinline__ bf16x8 cvt2(const float4& a, const float4& b) {
  return bf16x8{(bf16_t)a.x,(bf16_t)a.y,(bf16_t)a.z,(bf16_t)a.w,
                (bf16_t)b.x,(bf16_t)b.y,(bf16_t)b.z,(bf16_t)b.w};
}

// pack two f32 -> one 32-bit word of 2 bf16 (lo=a, hi=b), RTNE
static __device__ __forceinline__ uint32_t pk2(float a, float b) {
  uint32_t r;
  asm("v_cvt_pk_bf16_f32 %0, %1, %2" : "=v"(r) : "v"(a), "v"(b));
  return r;
}

// ---------------------------------------------------------------------------
// cvt_bf16: one streaming pass converting all GEMM operands to bf16.
// ---------------------------------------------------------------------------
__global__ void __launch_bounds__(256)
cvt_bf16(const float* __restrict__ q, const float* __restrict__ k,
         const float* __restrict__ v, const float* __restrict__ Wq,
         const float* __restrict__ Wk, const float* __restrict__ Wv,
         const float* __restrict__ Wo,
         bf16_t* __restrict__ qb, bf16_t* __restrict__ kb,
         bf16_t* __restrict__ vb, bf16_t* __restrict__ wq,
         bf16_t* __restrict__ wk, bf16_t* __restrict__ wv,
         bf16_t* __restrict__ wo)
{
  const int CQ = 524288;             // chunks per q/k/v tensor (8 elems each)
  const int CW = 32768;              // chunks per W
  const int TOT = 3 * CQ + 4 * CW;   // 1,703,936
  const int STRIDE = 2048 * 256;
  for (int c = blockIdx.x * 256 + threadIdx.x; c < TOT; c += STRIDE) {
    const float* src; bf16_t* dst; int off;
    if (c < 3 * CQ) {
      const int t = c >> 19;
      const int r = c & (CQ - 1);
      src = (t == 0) ? q : (t == 1) ? k : v;
      dst = (t == 0) ? qb : (t == 1) ? kb : vb;
      off = r << 3;
    } else {
      const int c2 = c - 3 * CQ;
      const int t = c2 >> 15;
      const int r = c2 & (CW - 1);
      src = (t == 0) ? Wq : (t == 1) ? Wk : (t == 2) ? Wv : Wo;
      dst = (t == 0) ? wq : (t == 1) ? wk : (t == 2) ? wv : wo;
      off = r << 3;
    }
    const float4 a = *(const float4*)(src + off);
    const float4 b = *(const float4*)(src + off + 4);
    *(bf16x8*)(dst + off) = cvt2(a, b);
  }
}

// ---------------------------------------------------------------------------
// qkv_proj: all three projections in ONE dispatch, bf16 in (R5 config,
// plain Vt[B,H,D,N] epilogue).
// ---------------------------------------------------------------------------
__global__ void __launch_bounds__(256, 3)
qkv_proj(const bf16_t* __restrict__ qb, const bf16_t* __restrict__ kb,
         const bf16_t* __restrict__ vb,
         const bf16_t* __restrict__ Wqb, const float* __restrict__ bq,
         const bf16_t* __restrict__ Wkb, const float* __restrict__ bk,
         const bf16_t* __restrict__ Wvb, const float* __restrict__ bv,
         bf16_t* __restrict__ Qp, bf16_t* __restrict__ Kp,
         bf16_t* __restrict__ Vt, float qscale)
{
  __shared__ __align__(16) bf16_t S[2 * 128 * 72];   // As | Bs, 36,864 B
  bf16_t* As = S;
  bf16_t* Bs = S + 128 * 72;

  const int l     = blockIdx.x;                  // 0..767
  const int slice = l >> 8;                      // 0=Q, 1=K, 2=V
  const int inner = l & 255;
  const int mtile = ((inner & 7) << 3) | (inner >> 5);  // 0..63, XCD-contig
  const int ntile = (inner >> 3) & 3;                   // 0..3
  const int tid   = threadIdx.x;
  const int w     = tid >> 6;
  const int lane  = tid & 63;
  const int lr    = lane & 15;
  const int quad  = lane >> 4;
  const int wm    = w & 1;
  const int wn    = w >> 1;
  const int xrow  = tid >> 1, xcol = (tid & 1) << 5;  // stage: 128 rows x 64 cols

  const bf16_t* Xb   = (slice == 0) ? qb  : (slice == 1) ? kb  : vb;
  const bf16_t* W    = (slice == 0) ? Wqb : (slice == 1) ? Wkb : Wvb;
  const float*  bias = (slice == 0) ? bq  : (slice == 1) ? bk  : bv;
  const float scale  = (slice == 0) ? qscale : 1.0f;

  float bvv[4];
#pragma unroll
  for (int ci = 0; ci < 4; ++ci) bvv[ci] = bias[ntile * 128 + wn * 64 + ci * 16 + lr];

  f32x4 acc[4][4] = {};
  bf16x8 xa[4], wa[4];

#pragma unroll
  for (int j = 0; j < 4; ++j) {
    xa[j] = *(const bf16x8*)(Xb + (size_t)(mtile * 128 + xrow) * 512 + xcol + j * 8);
    wa[j] = *(const bf16x8*)(W  + (size_t)(ntile * 128 + xrow) * 512 + xcol + j * 8);
  }
#pragma unroll
  for (int j = 0; j < 4; ++j) {
    *(bf16x8*)(&As[xrow * 72 + xcol + j * 8]) = xa[j];
    *(bf16x8*)(&Bs[xrow * 72 + xcol + j * 8]) = wa[j];
  }
  __syncthreads();

  for (int it = 0; it < 8; ++it) {
    if (it != 7) {
      const int k0 = (it + 1) << 6;
#pragma unroll
      for (int j = 0; j < 4; ++j) {
        xa[j] = *(const bf16x8*)(Xb + (size_t)(mtile * 128 + xrow) * 512 + k0 + xcol + j * 8);
        wa[j] = *(const bf16x8*)(W  + (size_t)(ntile * 128 + xrow) * 512 + k0 + xcol + j * 8);
      }
    }
    bf16x8 af[4][2], bfr[4][2];
#pragma unroll
    for (int mi = 0; mi < 4; ++mi)
#pragma unroll
      for (int kh = 0; kh < 2; ++kh)
        af[mi][kh] = *(const bf16x8*)(&As[(wm * 64 + mi * 16 + lr) * 72 + (kh * 4 + quad) * 8]);
#pragma unroll
    for (int ci = 0; ci < 4; ++ci)
#pragma unroll
      for (int kh = 0; kh < 2; ++kh)
        bfr[ci][kh] = *(const bf16x8*)(&Bs[(wn * 64 + ci * 16 + lr) * 72 + (kh * 4 + quad) * 8]);
#pragma unroll
    for (int mi = 0; mi < 4; ++mi)
#pragma unroll
      for (int ci = 0; ci < 4; ++ci) {
        acc[mi][ci] = MFMA_BF16(af[mi][0], bfr[ci][0], acc[mi][ci], 0, 0, 0);
        acc[mi][ci] = MFMA_BF16(af[mi][1], bfr[ci][1], acc[mi][ci], 0, 0, 0);
      }
    __syncthreads();
    if (it != 7) {
#pragma unroll
      for (int j = 0; j < 4; ++j) {
        *(bf16x8*)(&As[xrow * 72 + xcol + j * 8]) = xa[j];
        *(bf16x8*)(&Bs[xrow * 72 + xcol + j * 8]) = wa[j];
      }
      __syncthreads();
    }
  }

  // ---- epilogue: LDS-staged coalesced stores ----
  bf16_t (*Ct)[136] = (bf16_t (*)[136])S;   // 128x136 bf16
  if (slice < 2) {
    bf16_t* outQK = (slice == 0) ? Qp : Kp;
#pragma unroll
    for (int mi = 0; mi < 4; ++mi)
#pragma unroll
      for (int ci = 0; ci < 4; ++ci)
#pragma unroll
        for (int r = 0; r < 4; ++r)
          Ct[wm * 64 + mi * 16 + quad * 4 + r][wn * 64 + ci * 16 + lr] =
              (bf16_t)((acc[mi][ci][r] + bvv[ci]) * scale);
    __syncthreads();
    const int r2 = tid >> 1, half = tid & 1;
    const int gm = mtile * 128 + r2;
    const int b = gm >> 12, n = gm & 4095;
    const int gc0 = ntile * 128 + half * 64;
    const int h = gc0 >> 6;
    bf16_t* dst = outQK + (size_t)((b * 8 + h) * 4096 + n) * 64;
#pragma unroll
    for (int j = 0; j < 8; ++j)
      *(bf16x8*)(dst + j * 8) = *(const bf16x8*)(&Ct[r2][half * 64 + j * 8]);
  } else {
    // V: transpose in LDS -> Vt[B,H,D,N] rows of contiguous n
#pragma unroll
    for (int mi = 0; mi < 4; ++mi)
#pragma unroll
      for (int ci = 0; ci < 4; ++ci)
#pragma unroll
        for (int r = 0; r < 4; ++r)
          Ct[wn * 64 + ci * 16 + lr][wm * 64 + mi * 16 + quad * 4 + r] =
              (bf16_t)(acc[mi][ci][r] + bvv[ci]);
    __syncthreads();
    const int dline = tid >> 1, half = tid & 1;
    const int gc = ntile * 128 + dline;
    const int h = gc >> 6, dd = gc & 63;
    const int b = (mtile * 128) >> 12;
    const int n0 = (mtile * 128) & 4095;
    bf16_t* dst = Vt + (size_t)((b * 8 + h) * 64 + dd) * 4096 + n0 + half * 64;
#pragma unroll
    for (int j = 0; j < 8; ++j)
      *(bf16x8*)(dst + j * 8) = *(const bf16x8*)(&Ct[dline][half * 64 + j * 8]);
  }
}

// ---------------------------------------------------------------------------
// o_proj: final projection, f32 out [B,N,E] (unchanged R5).
// ---------------------------------------------------------------------------
__global__ void __launch_bounds__(256, 4)
o_proj(const bf16_t* __restrict__ Xb, const bf16_t* __restrict__ W,
       const float* __restrict__ bias, float* __restrict__ out)
{
  __shared__ __align__(16) bf16_t As[64 * 72];
  __shared__ __align__(16) bf16_t Bs[64 * 72];
  const int l     = blockIdx.x;
  const int mtile = ((l & 7) << 4) | ((l >> 3) & 15);  // 0..127, XCD-contig
  const int ntile = l >> 7;                            // 0..7
  const int tid   = threadIdx.x;
  const int w     = tid >> 6;
  const int lane  = tid & 63;
  const int lr    = lane & 15;
  const int quad  = lane >> 4;
  const int wm    = w & 1;
  const int wn    = w >> 1;
  const int xrow  = tid >> 2, xcol = (tid & 3) << 4;  // 64 rows x 64 cols

  float bvv[2];
#pragma unroll
  for (int ci = 0; ci < 2; ++ci) bvv[ci] = bias[ntile * 64 + wn * 32 + ci * 16 + lr];

  f32x4 acc[2][2] = {};
  bf16x8 xb[2], wb[2];

#pragma unroll
  for (int j = 0; j < 2; ++j) {
    xb[j] = *(const bf16x8*)(Xb + (size_t)(mtile * 64 + xrow) * 512 + xcol + j * 8);
    wb[j] = *(const bf16x8*)(W  + (size_t)(ntile * 64 + xrow) * 512 + xcol + j * 8);
  }
#pragma unroll
  for (int j = 0; j < 2; ++j) {
    *(bf16x8*)(&As[xrow * 72 + xcol + j * 8]) = xb[j];
    *(bf16x8*)(&Bs[xrow * 72 + xcol + j * 8]) = wb[j];
  }
  __syncthreads();

  for (int it = 0; it < 8; ++it) {
    if (it != 7) {
      const int k0 = (it + 1) << 6;
#pragma unroll
      for (int j = 0; j < 2; ++j) {
        xb[j] = *(const bf16x8*)(Xb + (size_t)(mtile * 64 + xrow) * 512 + k0 + xcol + j * 8);
        wb[j] = *(const bf16x8*)(W  + (size_t)(ntile * 64 + xrow) * 512 + k0 + xcol + j * 8);
      }
    }
    bf16x8 af[2][2], bfr[2][2];
#pragma unroll
    for (int mi = 0; mi < 2; ++mi)
#pragma unroll
      for (int kh = 0; kh < 2; ++kh)
        af[mi][kh] = *(const bf16x8*)(&As[(wm * 32 + mi * 16 + lr) * 72 + (kh * 4 + quad) * 8]);
#pragma unroll
    for (int ci = 0; ci < 2; ++ci)
#pragma unroll
      for (int kh = 0; kh < 2; ++kh)
        bfr[ci][kh] = *(const bf16x8*)(&Bs[(wn * 32 + ci * 16 + lr) * 72 + (kh * 4 + quad) * 8]);
#pragma unroll
    for (int mi = 0; mi < 2; ++mi)
#pragma unroll
      for (int ci = 0; ci < 2; ++ci) {
        acc[mi][ci] = MFMA_BF16(af[mi][0], bfr[ci][0], acc[mi][ci], 0, 0, 0);
        acc[mi][ci] = MFMA_BF16(af[mi][1], bfr[ci][1], acc[mi][ci], 0, 0, 0);
      }
    __syncthreads();
    if (it != 7) {
#pragma unroll
      for (int j = 0; j < 2; ++j) {
        *(bf16x8*)(&As[xrow * 72 + xcol + j * 8]) = xb[j];
        *(bf16x8*)(&Bs[xrow * 72 + xcol + j * 8]) = wb[j];
      }
      __syncthreads();
    }
  }

#pragma unroll
  for (int mi = 0; mi < 2; ++mi) {
    const int gm0 = mtile * 64 + wm * 32 + mi * 16 + quad * 4;
#pragma unroll
    for (int ci = 0; ci < 2; ++ci) {
      const int gc = ntile * 64 + wn * 32 + ci * 16 + lr;
#pragma unroll
      for (int r = 0; r < 4; ++r)
        out[(size_t)(gm0 + r) * 512 + gc] = acc[mi][ci][r] + bvv[ci];
    }
  }
}

// ---------------------------------------------------------------------------
// flash_attn v16: v11 structure verbatim (86us verified): 512 thr = 8 waves,
// grid (16,32), 2 blocks/CU -> 16 waves/CU. Group g = wave>>2: g0 = KV
// chunks 0..31, g1 = 32..63; private dbuf K/V LDS per group (73,728 B).
// 32 q-rows/wave, transposed S, m=0 softmax, in-register P exchange.
// Only delta vs v11: padded f32 merge (acc stride 33 dwords, lsum stride 3
// — verified correct in R9's v14; removes the 64-way merge bank conflict).
// No setprio (R9: -11us regression).
// ---------------------------------------------------------------------------
__global__ void __launch_bounds__(512, 2)
flash_attn(const bf16_t* __restrict__ Qp, const bf16_t* __restrict__ Kp,
           const bf16_t* __restrict__ Vt, bf16_t* __restrict__ Oc)
{
  __shared__ __align__(16) bf16_t Klds[2][2][64 * 72];   // [g][buf]
  __shared__ __align__(16) bf16_t Vlds[2][2][64 * 72];

  const int tid  = threadIdx.x;
  const int w    = tid >> 6;               // 0..7
  const int g    = w >> 2;                 // 0..1  (KV half)
  const int wl   = w & 3;                  // 0..3  (q sub-tile)
  const int lane = tid & 63, lr = lane & 15, quad = lane >> 4;
  const int bh   = blockIdx.x;
  const int qt0  = blockIdx.y * 128 + wl * 32;

  const bf16_t* Qh = Qp + (size_t)bh * 4096 * 64;
  const bf16_t* Kh = Kp + (size_t)bh * 4096 * 64;
  const bf16_t* Vh = Vt + (size_t)bh * 64 * 4096;

  const int tg   = tid & 255;              // thread-in-group
  const int srow = tg >> 2;                // 0..63
  const int scol = (tg & 3) << 4;          // 0,16,32,48
  const int kvbase = g << 11;              // g*32 chunks * 64 rows

  bf16x8 qf[2][2];
#pragma unroll
  for (int qi = 0; qi < 2; ++qi)
#pragma unroll
    for (int kh = 0; kh < 2; ++kh)
      qf[qi][kh] = *(const bf16x8*)(Qh + (size_t)(qt0 + qi * 16 + lr) * 64 + kh * 32 + quad * 8);

  bf16x8 kst[2], vst[2];
#pragma unroll
  for (int j = 0; j < 2; ++j) {
    kst[j] = *(const bf16x8*)(Kh + (size_t)(kvbase + srow) * 64 + scol + j * 8);
    vst[j] = *(const bf16x8*)(Vh + (size_t)srow * 4096 + kvbase + scol + j * 8);
  }
#pragma unroll
  for (int j = 0; j < 2; ++j) {
    *(bf16x8*)(&Klds[g][0][srow * 72 + scol + j * 8]) = kst[j];
    *(bf16x8*)(&Vlds[g][0][srow * 72 + scol + j * 8]) = vst[j];
  }
  __syncthreads();

  f32x4 acc[2][4] = {};
  float lsum[2] = {0.f, 0.f};
  const f32x4 zero = {0.f, 0.f, 0.f, 0.f};

  for (int it = 0; it < 32; ++it) {
    const int cur = it & 1, nxt = cur ^ 1;

    if (it != 31) {
      const int kvn = kvbase + ((it + 1) << 6);
#pragma unroll
      for (int j = 0; j < 2; ++j) {
        kst[j] = *(const bf16x8*)(Kh + (size_t)(kvn + srow) * 64 + scol + j * 8);
        vst[j] = *(const bf16x8*)(Vh + (size_t)srow * 4096 + kvn + scol + j * 8);
      }
    }

    bf16x8 kf[4][2];
#pragma unroll
    for (int mt = 0; mt < 4; ++mt)
#pragma unroll
      for (int kh = 0; kh < 2; ++kh)
        kf[mt][kh] = *(const bf16x8*)(&Klds[g][cur][(mt * 16 + lr) * 72 + (kh * 4 + quad) * 8]);
    bf16x8 vf[4][2];
#pragma unroll
    for (int t = 0; t < 4; ++t)
#pragma unroll
      for (int kvh = 0; kvh < 2; ++kvh)
        vf[t][kvh] = *(const bf16x8*)(&Vlds[g][cur][(t * 16 + lr) * 72 + (kvh * 4 + quad) * 8]);

    f32x4 sT[4][2];
#pragma unroll
    for (int mt = 0; mt < 4; ++mt)
#pragma unroll
      for (int qi = 0; qi < 2; ++qi) {
        sT[mt][qi] = MFMA_BF16(kf[mt][0], qf[qi][0], zero, 0, 0, 0);
        sT[mt][qi] = MFMA_BF16(kf[mt][1], qf[qi][1], sT[mt][qi], 0, 0, 0);
      }

    // softmax + in-register P exchange (S^T C-layout -> PV A-frag layout)
    bf16x8 pa[2][2];
#pragma unroll
    for (int qi = 0; qi < 2; ++qi) {
      uint32_t ap[4], bp[4];
#pragma unroll
      for (int mt = 0; mt < 4; ++mt) {
        float p0 = __builtin_amdgcn_exp2f(sT[mt][qi][0]);
        float p1 = __builtin_amdgcn_exp2f(sT[mt][qi][1]);
        float p2 = __builtin_amdgcn_exp2f(sT[mt][qi][2]);
        float p3 = __builtin_amdgcn_exp2f(sT[mt][qi][3]);
        lsum[qi] += (p0 + p1) + (p2 + p3);
        ap[mt] = pk2(p0, p1);
        bp[mt] = pk2(p2, p3);
      }
#pragma unroll
      for (int kvh = 0; kvh < 2; ++kvh) {
        uint32_t xa_ = ap[2 * kvh], ya_ = ap[2 * kvh + 1];
        asm("v_permlane32_swap_b32 %0, %1" : "+v"(xa_), "+v"(ya_));
        asm("v_permlane16_swap_b32 %0, %1" : "+v"(xa_), "+v"(ya_));
        uint32_t xb_ = bp[2 * kvh], yb_ = bp[2 * kvh + 1];
        asm("v_permlane32_swap_b32 %0, %1" : "+v"(xb_), "+v"(yb_));
        asm("v_permlane16_swap_b32 %0, %1" : "+v"(xb_), "+v"(yb_));
        union { uint32_t u[4]; bf16x8 v; } pu;
        pu.u[0] = xa_; pu.u[1] = xb_; pu.u[2] = ya_; pu.u[3] = yb_;
        pa[qi][kvh] = pu.v;
      }
    }

#pragma unroll
    for (int t = 0; t < 4; ++t)
#pragma unroll
      for (int qi = 0; qi < 2; ++qi) {
        acc[qi][t] = MFMA_BF16(pa[qi][0], vf[t][0], acc[qi][t], 0, 0, 0);
        acc[qi][t] = MFMA_BF16(pa[qi][1], vf[t][1], acc[qi][t], 0, 0, 0);
      }

    if (it != 31) {
#pragma unroll
      for (int j = 0; j < 2; ++j) {
        *(bf16x8*)(&Klds[g][nxt][srow * 72 + scol + j * 8]) = kst[j];
        *(bf16x8*)(&Vlds[g][nxt][srow * 72 + scol + j * 8]) = vst[j];
      }
    }
    __syncthreads();
  }

  // intra-wave reduce lsum across quads (each lane ends with its lr-row sum)
#pragma unroll
  for (int qi = 0; qi < 2; ++qi) {
    lsum[qi] += __shfl_xor(lsum[qi], 16);
    lsum[qi] += __shfl_xor(lsum[qi], 32);
  }

  // ---- merge g1 -> g0 via LDS (K staging is dead; padded strides) ----
  // accM: [4 waves][64 lanes][33 f32] = 33,792 B; lsumM: [4][64][3] = 3,072 B
  // -> 36,864 B = the dead Klds region. Stride 33/3 dwords avoids the
  // stride-32 64-way bank conflict (verified correct + effective in R9).
  float* accM  = (float*)&Klds[0][0][0];
  float* lsumM = accM + 4 * 64 * 33;
  const int mslot = (wl * 64 + lane);
  if (g == 1) {
#pragma unroll
    for (int qi = 0; qi < 2; ++qi) {
      lsumM[mslot * 3 + qi] = lsum[qi];
#pragma unroll
      for (int t = 0; t < 4; ++t)
#pragma unroll
        for (int r = 0; r < 4; ++r)
          accM[mslot * 33 + qi * 16 + t * 4 + r] = acc[qi][t][r];
    }
  }
  __syncthreads();
  if (g == 1) return;

#pragma unroll
  for (int qi = 0; qi < 2; ++qi) {
    lsum[qi] += lsumM[mslot * 3 + qi];
#pragma unroll
    for (int t = 0; t < 4; ++t)
#pragma unroll
      for (int r = 0; r < 4; ++r)
        acc[qi][t][r] += accM[mslot * 33 + qi * 16 + t * 4 + r];
  }

  const int b = bh >> 3, h = bh & 7;
  bf16_t* Ob = Oc + (size_t)b * 4096 * 512 + h * 64;
#pragma unroll
  for (int qi = 0; qi < 2; ++qi) {
    float inv[4];
#pragma unroll
    for (int r = 0; r < 4; ++r)
      inv[r] = 1.0f / __shfl(lsum[qi], quad * 4 + r);
#pragma unroll
    for (int t = 0; t < 4; ++t)
#pragma unroll
      for (int r = 0; r < 4; ++r) {
        const int n = qt0 + qi * 16 + quad * 4 + r;
        Ob[(size_t)n * 512 + t * 16 + lr] = (bf16_t)(acc[qi][t][r] * inv[r]);
      }
  }
}

// ---------------------------------------------------------------------------
extern "C" void kernel_launch(void* const* d_in, const int* in_sizes, int n_in,
                              void* d_out, int out_size, void* d_ws, size_t ws_size,
                              hipStream_t stream)
{
  const float* q  = (const float*)d_in[0];
  const float* k  = (const float*)d_in[1];
  const float* v  = (const float*)d_in[2];
  const float* Wq = (const float*)d_in[3];
  const float* bq = (const float*)d_in[4];
  const float* Wk = (const float*)d_in[5];
  const float* bk = (const float*)d_in[6];
  const float* Wv = (const float*)d_in[7];
  const float* bv = (const float*)d_in[8];
  const float* Wo = (const float*)d_in[9];
  const float* bo = (const float*)d_in[10];

  const size_t HEAD_ELEMS = (size_t)2 * 8 * 4096 * 64;  // 4,194,304 (8 MB bf16)
  const size_t W_ELEMS    = (size_t)512 * 512;          // 262,144

  bf16_t* base = (bf16_t*)d_ws;
  bf16_t* qb  = base;                        // [B,N,E] bf16
  bf16_t* kb  = qb + HEAD_ELEMS;
  bf16_t* vb  = kb + HEAD_ELEMS;
  bf16_t* Qp  = vb + HEAD_ELEMS;             // [B,H,N,D], pre-scaled
  bf16_t* Kp  = Qp + HEAD_ELEMS;             // [B,H,N,D]
  bf16_t* Vt  = Kp + HEAD_ELEMS;             // [B,H,D,N]
  bf16_t* wqb = Vt + HEAD_ELEMS;
  bf16_t* wkb = wqb + W_ELEMS;
  bf16_t* wvb = wkb + W_ELEMS;
  bf16_t* wob = wvb + W_ELEMS;
  bf16_t* Oc  = qb;   // aliases qb: dead after qkv_proj, Oc written by flash

  const float qscale = 0.125f * 1.44269504f;  // 1/sqrt(D) * log2(e)

  cvt_bf16<<<dim3(2048), 256, 0, stream>>>(q, k, v, Wq, Wk, Wv, Wo,
                                           qb, kb, vb, wqb, wkb, wvb, wob);
  qkv_proj<<<dim3(768), 256, 0, stream>>>(qb, kb, vb, wqb, bq, wkb, bk,
                                          wvb, bv, Qp, Kp, Vt, qscale);
  flash_attn<<<dim3(16, 32), 512, 0, stream>>>(Qp, Kp, Vt, Oc);
  o_proj<<<dim3(1024), 256, 0, stream>>>(Oc, wob, bo, (float*)d_out);
}

// Round 13
// 215.347 us; speedup vs baseline: 1.0595x; 1.0285x over previous
//
#include <hip/hip_runtime.h>
#include <hip/hip_bf16.h>
#include <cstddef>
#include <cstdint>

// MHA: B=2, N=4096, E=512, H=8, D=64.
// Pipeline: cvt_bf16 -> qkv_proj (768 blocks, 128x128 tile, single-buf LDS,
// 3/CU, XCD remap; COALESCED Q/K epilogue: 128B-run stores, 8 segments/instr
// instead of 64; plain Vt[B,H,D,N] epilogue) -> flash v16 (R11-verified:
// v11 KV-split 512-thr/8-wave + padded f32 merge, 83.1us) -> o_proj (64x64,
// grid 1024, 4/CU). Workspace: qb/kb/vb (Oc aliases qb), Qp/Kp/Vt, w*b.
// (R12 resubmission — container failed twice; kernel never measured.)

typedef __bf16 bf16_t;
typedef __bf16 bf16x8 __attribute__((ext_vector_type(8)));
typedef __bf16 bf16x4 __attribute__((ext_vector_type(4)));
typedef float  f32x4  __attribute__((ext_vector_type(4)));

#define MFMA_BF16 __builtin_amdgcn_mfma_f32_16x16x32_bf16

static __device__ __forceinline__ bf16x8 cvt2(const float4& a, const float4& b) {
  return bf16x8{(bf16_t)a.x,(bf16_t)a.y,(bf16_t)a.z,(bf16_t)a.w,
                (bf16_t)b.x,(bf16_t)b.y,(bf16_t)b.z,(bf16_t)b.w};
}

// pack two f32 -> one 32-bit word of 2 bf16 (lo=a, hi=b), RTNE
static __device__ __forceinline__ uint32_t pk2(float a, float b) {
  uint32_t r;
  asm("v_cvt_pk_bf16_f32 %0, %1, %2" : "=v"(r) : "v"(a), "v"(b));
  return r;
}

// ---------------------------------------------------------------------------
// cvt_bf16: one streaming pass converting all GEMM operands to bf16.
// ---------------------------------------------------------------------------
__global__ void __launch_bounds__(256)
cvt_bf16(const float* __restrict__ q, const float* __restrict__ k,
         const float* __restrict__ v, const float* __restrict__ Wq,
         const float* __restrict__ Wk, const float* __restrict__ Wv,
         const float* __restrict__ Wo,
         bf16_t* __restrict__ qb, bf16_t* __restrict__ kb,
         bf16_t* __restrict__ vb, bf16_t* __restrict__ wq,
         bf16_t* __restrict__ wk, bf16_t* __restrict__ wv,
         bf16_t* __restrict__ wo)
{
  const int CQ = 524288;             // chunks per q/k/v tensor (8 elems each)
  const int CW = 32768;              // chunks per W
  const int TOT = 3 * CQ + 4 * CW;   // 1,703,936
  const int STRIDE = 2048 * 256;
  for (int c = blockIdx.x * 256 + threadIdx.x; c < TOT; c += STRIDE) {
    const float* src; bf16_t* dst; int off;
    if (c < 3 * CQ) {
      const int t = c >> 19;
      const int r = c & (CQ - 1);
      src = (t == 0) ? q : (t == 1) ? k : v;
      dst = (t == 0) ? qb : (t == 1) ? kb : vb;
      off = r << 3;
    } else {
      const int c2 = c - 3 * CQ;
      const int t = c2 >> 15;
      const int r = c2 & (CW - 1);
      src = (t == 0) ? Wq : (t == 1) ? Wk : (t == 2) ? Wv : Wo;
      dst = (t == 0) ? wq : (t == 1) ? wk : (t == 2) ? wv : wo;
      off = r << 3;
    }
    const float4 a = *(const float4*)(src + off);
    const float4 b = *(const float4*)(src + off + 4);
    *(bf16x8*)(dst + off) = cvt2(a, b);
  }
}

// ---------------------------------------------------------------------------
// qkv_proj: all three projections in ONE dispatch, bf16 in.
// Q/K epilogue: 128B-run coalesced stores (8 passes; lane group j8 = one run).
// ---------------------------------------------------------------------------
__global__ void __launch_bounds__(256, 3)
qkv_proj(const bf16_t* __restrict__ qb, const bf16_t* __restrict__ kb,
         const bf16_t* __restrict__ vb,
         const bf16_t* __restrict__ Wqb, const float* __restrict__ bq,
         const bf16_t* __restrict__ Wkb, const float* __restrict__ bk,
         const bf16_t* __restrict__ Wvb, const float* __restrict__ bv,
         bf16_t* __restrict__ Qp, bf16_t* __restrict__ Kp,
         bf16_t* __restrict__ Vt, float qscale)
{
  __shared__ __align__(16) bf16_t S[2 * 128 * 72];   // As | Bs, 36,864 B
  bf16_t* As = S;
  bf16_t* Bs = S + 128 * 72;

  const int l     = blockIdx.x;                  // 0..767
  const int slice = l >> 8;                      // 0=Q, 1=K, 2=V
  const int inner = l & 255;
  const int mtile = ((inner & 7) << 3) | (inner >> 5);  // 0..63, XCD-contig
  const int ntile = (inner >> 3) & 3;                   // 0..3
  const int tid   = threadIdx.x;
  const int w     = tid >> 6;
  const int lane  = tid & 63;
  const int lr    = lane & 15;
  const int quad  = lane >> 4;
  const int wm    = w & 1;
  const int wn    = w >> 1;
  const int xrow  = tid >> 1, xcol = (tid & 1) << 5;  // stage: 128 rows x 64 cols

  const bf16_t* Xb   = (slice == 0) ? qb  : (slice == 1) ? kb  : vb;
  const bf16_t* W    = (slice == 0) ? Wqb : (slice == 1) ? Wkb : Wvb;
  const float*  bias = (slice == 0) ? bq  : (slice == 1) ? bk  : bv;
  const float scale  = (slice == 0) ? qscale : 1.0f;

  float bvv[4];
#pragma unroll
  for (int ci = 0; ci < 4; ++ci) bvv[ci] = bias[ntile * 128 + wn * 64 + ci * 16 + lr];

  f32x4 acc[4][4] = {};
  bf16x8 xa[4], wa[4];

#pragma unroll
  for (int j = 0; j < 4; ++j) {
    xa[j] = *(const bf16x8*)(Xb + (size_t)(mtile * 128 + xrow) * 512 + xcol + j * 8);
    wa[j] = *(const bf16x8*)(W  + (size_t)(ntile * 128 + xrow) * 512 + xcol + j * 8);
  }
#pragma unroll
  for (int j = 0; j < 4; ++j) {
    *(bf16x8*)(&As[xrow * 72 + xcol + j * 8]) = xa[j];
    *(bf16x8*)(&Bs[xrow * 72 + xcol + j * 8]) = wa[j];
  }
  __syncthreads();

  for (int it = 0; it < 8; ++it) {
    if (it != 7) {
      const int k0 = (it + 1) << 6;
#pragma unroll
      for (int j = 0; j < 4; ++j) {
        xa[j] = *(const bf16x8*)(Xb + (size_t)(mtile * 128 + xrow) * 512 + k0 + xcol + j * 8);
        wa[j] = *(const bf16x8*)(W  + (size_t)(ntile * 128 + xrow) * 512 + k0 + xcol + j * 8);
      }
    }
    bf16x8 af[4][2], bfr[4][2];
#pragma unroll
    for (int mi = 0; mi < 4; ++mi)
#pragma unroll
      for (int kh = 0; kh < 2; ++kh)
        af[mi][kh] = *(const bf16x8*)(&As[(wm * 64 + mi * 16 + lr) * 72 + (kh * 4 + quad) * 8]);
#pragma unroll
    for (int ci = 0; ci < 4; ++ci)
#pragma unroll
      for (int kh = 0; kh < 2; ++kh)
        bfr[ci][kh] = *(const bf16x8*)(&Bs[(wn * 64 + ci * 16 + lr) * 72 + (kh * 4 + quad) * 8]);
#pragma unroll
    for (int mi = 0; mi < 4; ++mi)
#pragma unroll
      for (int ci = 0; ci < 4; ++ci) {
        acc[mi][ci] = MFMA_BF16(af[mi][0], bfr[ci][0], acc[mi][ci], 0, 0, 0);
        acc[mi][ci] = MFMA_BF16(af[mi][1], bfr[ci][1], acc[mi][ci], 0, 0, 0);
      }
    __syncthreads();
    if (it != 7) {
#pragma unroll
      for (int j = 0; j < 4; ++j) {
        *(bf16x8*)(&As[xrow * 72 + xcol + j * 8]) = xa[j];
        *(bf16x8*)(&Bs[xrow * 72 + xcol + j * 8]) = wa[j];
      }
      __syncthreads();
    }
  }

  // ---- epilogue: LDS-staged coalesced stores ----
  bf16_t (*Ct)[136] = (bf16_t (*)[136])S;   // 128x136 bf16
  if (slice < 2) {
    bf16_t* outQK = (slice == 0) ? Qp : Kp;
#pragma unroll
    for (int mi = 0; mi < 4; ++mi)
#pragma unroll
      for (int ci = 0; ci < 4; ++ci)
#pragma unroll
        for (int r = 0; r < 4; ++r)
          Ct[wm * 64 + mi * 16 + quad * 4 + r][wn * 64 + ci * 16 + lr] =
              (bf16_t)((acc[mi][ci][r] + bvv[ci]) * scale);
    __syncthreads();
    // 256 runs of 128B: run R -> row=R>>1, h-half=R&1. 8 lanes per run
    // (slot = lane&7) -> one 128B contiguous segment per 8-lane group.
    const int j8 = lane >> 3, slot = lane & 7;
#pragma unroll
    for (int p = 0; p < 8; ++p) {
      const int R = p * 32 + w * 8 + j8;       // 0..255, bijective
      const int row = R >> 1, colHalf = R & 1;
      const int gm = mtile * 128 + row;
      const int b = gm >> 12, n = gm & 4095;
      const int h = ntile * 2 + colHalf;
      *(bf16x8*)(outQK + (size_t)((b * 8 + h) * 4096 + n) * 64 + slot * 8) =
          *(const bf16x8*)(&Ct[row][colHalf * 64 + slot * 8]);
    }
  } else {
    // V: transpose in LDS -> Vt[B,H,D,N] rows of contiguous n
#pragma unroll
    for (int mi = 0; mi < 4; ++mi)
#pragma unroll
      for (int ci = 0; ci < 4; ++ci)
#pragma unroll
        for (int r = 0; r < 4; ++r)
          Ct[wn * 64 + ci * 16 + lr][wm * 64 + mi * 16 + quad * 4 + r] =
              (bf16_t)(acc[mi][ci][r] + bvv[ci]);
    __syncthreads();
    const int dline = tid >> 1, half = tid & 1;
    const int gc = ntile * 128 + dline;
    const int h = gc >> 6, dd = gc & 63;
    const int b = (mtile * 128) >> 12;
    const int n0 = (mtile * 128) & 4095;
    bf16_t* dst = Vt + (size_t)((b * 8 + h) * 64 + dd) * 4096 + n0 + half * 64;
#pragma unroll
    for (int j = 0; j < 8; ++j)
      *(bf16x8*)(dst + j * 8) = *(const bf16x8*)(&Ct[dline][half * 64 + j * 8]);
  }
}

// ---------------------------------------------------------------------------
// o_proj: final projection, f32 out [B,N,E] (unchanged R5).
// ---------------------------------------------------------------------------
__global__ void __launch_bounds__(256, 4)
o_proj(const bf16_t* __restrict__ Xb, const bf16_t* __restrict__ W,
       const float* __restrict__ bias, float* __restrict__ out)
{
  __shared__ __align__(16) bf16_t As[64 * 72];
  __shared__ __align__(16) bf16_t Bs[64 * 72];
  const int l     = blockIdx.x;
  const int mtile = ((l & 7) << 4) | ((l >> 3) & 15);  // 0..127, XCD-contig
  const int ntile = l >> 7;                            // 0..7
  const int tid   = threadIdx.x;
  const int w     = tid >> 6;
  const int lane  = tid & 63;
  const int lr    = lane & 15;
  const int quad  = lane >> 4;
  const int wm    = w & 1;
  const int wn    = w >> 1;
  const int xrow  = tid >> 2, xcol = (tid & 3) << 4;  // 64 rows x 64 cols

  float bvv[2];
#pragma unroll
  for (int ci = 0; ci < 2; ++ci) bvv[ci] = bias[ntile * 64 + wn * 32 + ci * 16 + lr];

  f32x4 acc[2][2] = {};
  bf16x8 xb[2], wb[2];

#pragma unroll
  for (int j = 0; j < 2; ++j) {
    xb[j] = *(const bf16x8*)(Xb + (size_t)(mtile * 64 + xrow) * 512 + xcol + j * 8);
    wb[j] = *(const bf16x8*)(W  + (size_t)(ntile * 64 + xrow) * 512 + xcol + j * 8);
  }
#pragma unroll
  for (int j = 0; j < 2; ++j) {
    *(bf16x8*)(&As[xrow * 72 + xcol + j * 8]) = xb[j];
    *(bf16x8*)(&Bs[xrow * 72 + xcol + j * 8]) = wb[j];
  }
  __syncthreads();

  for (int it = 0; it < 8; ++it) {
    if (it != 7) {
      const int k0 = (it + 1) << 6;
#pragma unroll
      for (int j = 0; j < 2; ++j) {
        xb[j] = *(const bf16x8*)(Xb + (size_t)(mtile * 64 + xrow) * 512 + k0 + xcol + j * 8);
        wb[j] = *(const bf16x8*)(W  + (size_t)(ntile * 64 + xrow) * 512 + k0 + xcol + j * 8);
      }
    }
    bf16x8 af[2][2], bfr[2][2];
#pragma unroll
    for (int mi = 0; mi < 2; ++mi)
#pragma unroll
      for (int kh = 0; kh < 2; ++kh)
        af[mi][kh] = *(const bf16x8*)(&As[(wm * 32 + mi * 16 + lr) * 72 + (kh * 4 + quad) * 8]);
#pragma unroll
    for (int ci = 0; ci < 2; ++ci)
#pragma unroll
      for (int kh = 0; kh < 2; ++kh)
        bfr[ci][kh] = *(const bf16x8*)(&Bs[(wn * 32 + ci * 16 + lr) * 72 + (kh * 4 + quad) * 8]);
#pragma unroll
    for (int mi = 0; mi < 2; ++mi)
#pragma unroll
      for (int ci = 0; ci < 2; ++ci) {
        acc[mi][ci] = MFMA_BF16(af[mi][0], bfr[ci][0], acc[mi][ci], 0, 0, 0);
        acc[mi][ci] = MFMA_BF16(af[mi][1], bfr[ci][1], acc[mi][ci], 0, 0, 0);
      }
    __syncthreads();
    if (it != 7) {
#pragma unroll
      for (int j = 0; j < 2; ++j) {
        *(bf16x8*)(&As[xrow * 72 + xcol + j * 8]) = xb[j];
        *(bf16x8*)(&Bs[xrow * 72 + xcol + j * 8]) = wb[j];
      }
      __syncthreads();
    }
  }

#pragma unroll
  for (int mi = 0; mi < 2; ++mi) {
    const int gm0 = mtile * 64 + wm * 32 + mi * 16 + quad * 4;
#pragma unroll
    for (int ci = 0; ci < 2; ++ci) {
      const int gc = ntile * 64 + wn * 32 + ci * 16 + lr;
#pragma unroll
      for (int r = 0; r < 4; ++r)
        out[(size_t)(gm0 + r) * 512 + gc] = acc[mi][ci][r] + bvv[ci];
    }
  }
}

// ---------------------------------------------------------------------------
// flash_attn v16 (R11-verified, 83.1us): 512 thr = 8 waves, grid (16,32),
// 2 blocks/CU -> 16 waves/CU. Group g = wave>>2: g0 = KV chunks 0..31,
// g1 = 32..63; private dbuf K/V LDS per group (73,728 B). 32 q-rows/wave,
// transposed S, m=0 softmax, in-register P exchange. Padded f32 merge
// (stride 33/3). No setprio.
// ---------------------------------------------------------------------------
__global__ void __launch_bounds__(512, 2)
flash_attn(const bf16_t* __restrict__ Qp, const bf16_t* __restrict__ Kp,
           const bf16_t* __restrict__ Vt, bf16_t* __restrict__ Oc)
{
  __shared__ __align__(16) bf16_t Klds[2][2][64 * 72];   // [g][buf]
  __shared__ __align__(16) bf16_t Vlds[2][2][64 * 72];

  const int tid  = threadIdx.x;
  const int w    = tid >> 6;               // 0..7
  const int g    = w >> 2;                 // 0..1  (KV half)
  const int wl   = w & 3;                  // 0..3  (q sub-tile)
  const int lane = tid & 63, lr = lane & 15, quad = lane >> 4;
  const int bh   = blockIdx.x;
  const int qt0  = blockIdx.y * 128 + wl * 32;

  const bf16_t* Qh = Qp + (size_t)bh * 4096 * 64;
  const bf16_t* Kh = Kp + (size_t)bh * 4096 * 64;
  const bf16_t* Vh = Vt + (size_t)bh * 64 * 4096;

  const int tg   = tid & 255;              // thread-in-group
  const int srow = tg >> 2;                // 0..63
  const int scol = (tg & 3) << 4;          // 0,16,32,48
  const int kvbase = g << 11;              // g*32 chunks * 64 rows

  bf16x8 qf[2][2];
#pragma unroll
  for (int qi = 0; qi < 2; ++qi)
#pragma unroll
    for (int kh = 0; kh < 2; ++kh)
      qf[qi][kh] = *(const bf16x8*)(Qh + (size_t)(qt0 + qi * 16 + lr) * 64 + kh * 32 + quad * 8);

  bf16x8 kst[2], vst[2];
#pragma unroll
  for (int j = 0; j < 2; ++j) {
    kst[j] = *(const bf16x8*)(Kh + (size_t)(kvbase + srow) * 64 + scol + j * 8);
    vst[j] = *(const bf16x8*)(Vh + (size_t)srow * 4096 + kvbase + scol + j * 8);
  }
#pragma unroll
  for (int j = 0; j < 2; ++j) {
    *(bf16x8*)(&Klds[g][0][srow * 72 + scol + j * 8]) = kst[j];
    *(bf16x8*)(&Vlds[g][0][srow * 72 + scol + j * 8]) = vst[j];
  }
  __syncthreads();

  f32x4 acc[2][4] = {};
  float lsum[2] = {0.f, 0.f};
  const f32x4 zero = {0.f, 0.f, 0.f, 0.f};

  for (int it = 0; it < 32; ++it) {
    const int cur = it & 1, nxt = cur ^ 1;

    if (it != 31) {
      const int kvn = kvbase + ((it + 1) << 6);
#pragma unroll
      for (int j = 0; j < 2; ++j) {
        kst[j] = *(const bf16x8*)(Kh + (size_t)(kvn + srow) * 64 + scol + j * 8);
        vst[j] = *(const bf16x8*)(Vh + (size_t)srow * 4096 + kvn + scol + j * 8);
      }
    }

    bf16x8 kf[4][2];
#pragma unroll
    for (int mt = 0; mt < 4; ++mt)
#pragma unroll
      for (int kh = 0; kh < 2; ++kh)
        kf[mt][kh] = *(const bf16x8*)(&Klds[g][cur][(mt * 16 + lr) * 72 + (kh * 4 + quad) * 8]);
    bf16x8 vf[4][2];
#pragma unroll
    for (int t = 0; t < 4; ++t)
#pragma unroll
      for (int kvh = 0; kvh < 2; ++kvh)
        vf[t][kvh] = *(const bf16x8*)(&Vlds[g][cur][(t * 16 + lr) * 72 + (kvh * 4 + quad) * 8]);

    f32x4 sT[4][2];
#pragma unroll
    for (int mt = 0; mt < 4; ++mt)
#pragma unroll
      for (int qi = 0; qi < 2; ++qi) {
        sT[mt][qi] = MFMA_BF16(kf[mt][0], qf[qi][0], zero, 0, 0, 0);
        sT[mt][qi] = MFMA_BF16(kf[mt][1], qf[qi][1], sT[mt][qi], 0, 0, 0);
      }

    // softmax + in-register P exchange (S^T C-layout -> PV A-frag layout)
    bf16x8 pa[2][2];
#pragma unroll
    for (int qi = 0; qi < 2; ++qi) {
      uint32_t ap[4], bp[4];
#pragma unroll
      for (int mt = 0; mt < 4; ++mt) {
        float p0 = __builtin_amdgcn_exp2f(sT[mt][qi][0]);
        float p1 = __builtin_amdgcn_exp2f(sT[mt][qi][1]);
        float p2 = __builtin_amdgcn_exp2f(sT[mt][qi][2]);
        float p3 = __builtin_amdgcn_exp2f(sT[mt][qi][3]);
        lsum[qi] += (p0 + p1) + (p2 + p3);
        ap[mt] = pk2(p0, p1);
        bp[mt] = pk2(p2, p3);
      }
#pragma unroll
      for (int kvh = 0; kvh < 2; ++kvh) {
        uint32_t xa_ = ap[2 * kvh], ya_ = ap[2 * kvh + 1];
        asm("v_permlane32_swap_b32 %0, %1" : "+v"(xa_), "+v"(ya_));
        asm("v_permlane16_swap_b32 %0, %1" : "+v"(xa_), "+v"(ya_));
        uint32_t xb_ = bp[2 * kvh], yb_ = bp[2 * kvh + 1];
        asm("v_permlane32_swap_b32 %0, %1" : "+v"(xb_), "+v"(yb_));
        asm("v_permlane16_swap_b32 %0, %1" : "+v"(xb_), "+v"(yb_));
        union { uint32_t u[4]; bf16x8 v; } pu;
        pu.u[0] = xa_; pu.u[1] = xb_; pu.u[2] = ya_; pu.u[3] = yb_;
        pa[qi][kvh] = pu.v;
      }
    }

#pragma unroll
    for (int t = 0; t < 4; ++t)
#pragma unroll
      for (int qi = 0; qi < 2; ++qi) {
        acc[qi][t] = MFMA_BF16(pa[qi][0], vf[t][0], acc[qi][t], 0, 0, 0);
        acc[qi][t] = MFMA_BF16(pa[qi][1], vf[t][1], acc[qi][t], 0, 0, 0);
      }

    if (it != 31) {
#pragma unroll
      for (int j = 0; j < 2; ++j) {
        *(bf16x8*)(&Klds[g][nxt][srow * 72 + scol + j * 8]) = kst[j];
        *(bf16x8*)(&Vlds[g][nxt][srow * 72 + scol + j * 8]) = vst[j];
      }
    }
    __syncthreads();
  }

  // intra-wave reduce lsum across quads (each lane ends with its lr-row sum)
#pragma unroll
  for (int qi = 0; qi < 2; ++qi) {
    lsum[qi] += __shfl_xor(lsum[qi], 16);
    lsum[qi] += __shfl_xor(lsum[qi], 32);
  }

  // ---- merge g1 -> g0 via LDS (K staging is dead; padded strides) ----
  float* accM  = (float*)&Klds[0][0][0];
  float* lsumM = accM + 4 * 64 * 33;
  const int mslot = (wl * 64 + lane);
  if (g == 1) {
#pragma unroll
    for (int qi = 0; qi < 2; ++qi) {
      lsumM[mslot * 3 + qi] = lsum[qi];
#pragma unroll
      for (int t = 0; t < 4; ++t)
#pragma unroll
        for (int r = 0; r < 4; ++r)
          accM[mslot * 33 + qi * 16 + t * 4 + r] = acc[qi][t][r];
    }
  }
  __syncthreads();
  if (g == 1) return;

#pragma unroll
  for (int qi = 0; qi < 2; ++qi) {
    lsum[qi] += lsumM[mslot * 3 + qi];
#pragma unroll
    for (int t = 0; t < 4; ++t)
#pragma unroll
      for (int r = 0; r < 4; ++r)
        acc[qi][t][r] += accM[mslot * 33 + qi * 16 + t * 4 + r];
  }

  const int b = bh >> 3, h = bh & 7;
  bf16_t* Ob = Oc + (size_t)b * 4096 * 512 + h * 64;
#pragma unroll
  for (int qi = 0; qi < 2; ++qi) {
    float inv[4];
#pragma unroll
    for (int r = 0; r < 4; ++r)
      inv[r] = 1.0f / __shfl(lsum[qi], quad * 4 + r);
#pragma unroll
    for (int t = 0; t < 4; ++t)
#pragma unroll
      for (int r = 0; r < 4; ++r) {
        const int n = qt0 + qi * 16 + quad * 4 + r;
        Ob[(size_t)n * 512 + t * 16 + lr] = (bf16_t)(acc[qi][t][r] * inv[r]);
      }
  }
}

// ---------------------------------------------------------------------------
extern "C" void kernel_launch(void* const* d_in, const int* in_sizes, int n_in,
                              void* d_out, int out_size, void* d_ws, size_t ws_size,
                              hipStream_t stream)
{
  const float* q  = (const float*)d_in[0];
  const float* k  = (const float*)d_in[1];
  const float* v  = (const float*)d_in[2];
  const float* Wq = (const float*)d_in[3];
  const float* bq = (const float*)d_in[4];
  const float* Wk = (const float*)d_in[5];
  const float* bk = (const float*)d_in[6];
  const float* Wv = (const float*)d_in[7];
  const float* bv = (const float*)d_in[8];
  const float* Wo = (const float*)d_in[9];
  const float* bo = (const float*)d_in[10];

  const size_t HEAD_ELEMS = (size_t)2 * 8 * 4096 * 64;  // 4,194,304 (8 MB bf16)
  const size_t W_ELEMS    = (size_t)512 * 512;          // 262,144

  bf16_t* base = (bf16_t*)d_ws;
  bf16_t* qb  = base;                        // [B,N,E] bf16
  bf16_t* kb  = qb + HEAD_ELEMS;
  bf16_t* vb  = kb + HEAD_ELEMS;
  bf16_t* Qp  = vb + HEAD_ELEMS;             // [B,H,N,D], pre-scaled
  bf16_t* Kp  = Qp + HEAD_ELEMS;             // [B,H,N,D]
  bf16_t* Vt  = Kp + HEAD_ELEMS;             // [B,H,D,N]
  bf16_t* wqb = Vt + HEAD_ELEMS;
  bf16_t* wkb = wqb + W_ELEMS;
  bf16_t* wvb = wkb + W_ELEMS;
  bf16_t* wob = wvb + W_ELEMS;
  bf16_t* Oc  = qb;   // aliases qb: dead after qkv_proj, Oc written by flash

  const float qscale = 0.125f * 1.44269504f;  // 1/sqrt(D) * log2(e)

  cvt_bf16<<<dim3(2048), 256, 0, stream>>>(q, k, v, Wq, Wk, Wv, Wo,
                                           qb, kb, vb, wqb, wkb, wvb, wob);
  qkv_proj<<<dim3(768), 256, 0, stream>>>(qb, kb, vb, wqb, bq, wkb, bk,
                                          wvb, bv, Qp, Kp, Vt, qscale);
  flash_attn<<<dim3(16, 32), 512, 0, stream>>>(Qp, Kp, Vt, Oc);
  o_proj<<<dim3(1024), 256, 0, stream>>>(Oc, wob, bo, (float*)d_out);
}

// Round 14
// 214.180 us; speedup vs baseline: 1.0652x; 1.0055x over previous
//
#include <hip/hip_runtime.h>
#include <hip/hip_bf16.h>
#include <cstddef>
#include <cstdint>

// MHA: B=2, N=4096, E=512, H=8, D=64.
// Pipeline: cvt_bf16 -> qkv_proj (768 blocks, 128x128 tile, single-buf LDS,
// 3/CU, XCD remap; coalesced Q/K epilogue (R13-verified, -6us); plain
// Vt[B,H,D,N] epilogue) -> flash v16 (R11/R13-verified: v11 KV-split
// 512-thr/8-wave + padded f32 merge, 83-84us) -> o_proj (64x64, grid 1024,
// 4/CU; NEW: LDS-staged coalesced f32 epilogue, 256B runs).
// Workspace: qb/kb/vb (Oc aliases qb), Qp/Kp/Vt, w*b. ~52 MB.

typedef __bf16 bf16_t;
typedef __bf16 bf16x8 __attribute__((ext_vector_type(8)));
typedef __bf16 bf16x4 __attribute__((ext_vector_type(4)));
typedef float  f32x4  __attribute__((ext_vector_type(4)));

#define MFMA_BF16 __builtin_amdgcn_mfma_f32_16x16x32_bf16

static __device__ __forceinline__ bf16x8 cvt2(const float4& a, const float4& b) {
  return bf16x8{(bf16_t)a.x,(bf16_t)a.y,(bf16_t)a.z,(bf16_t)a.w,
                (bf16_t)b.x,(bf16_t)b.y,(bf16_t)b.z,(bf16_t)b.w};
}

// pack two f32 -> one 32-bit word of 2 bf16 (lo=a, hi=b), RTNE
static __device__ __forceinline__ uint32_t pk2(float a, float b) {
  uint32_t r;
  asm("v_cvt_pk_bf16_f32 %0, %1, %2" : "=v"(r) : "v"(a), "v"(b));
  return r;
}

// ---------------------------------------------------------------------------
// cvt_bf16: one streaming pass converting all GEMM operands to bf16.
// ---------------------------------------------------------------------------
__global__ void __launch_bounds__(256)
cvt_bf16(const float* __restrict__ q, const float* __restrict__ k,
         const float* __restrict__ v, const float* __restrict__ Wq,
         const float* __restrict__ Wk, const float* __restrict__ Wv,
         const float* __restrict__ Wo,
         bf16_t* __restrict__ qb, bf16_t* __restrict__ kb,
         bf16_t* __restrict__ vb, bf16_t* __restrict__ wq,
         bf16_t* __restrict__ wk, bf16_t* __restrict__ wv,
         bf16_t* __restrict__ wo)
{
  const int CQ = 524288;             // chunks per q/k/v tensor (8 elems each)
  const int CW = 32768;              // chunks per W
  const int TOT = 3 * CQ + 4 * CW;   // 1,703,936
  const int STRIDE = 2048 * 256;
  for (int c = blockIdx.x * 256 + threadIdx.x; c < TOT; c += STRIDE) {
    const float* src; bf16_t* dst; int off;
    if (c < 3 * CQ) {
      const int t = c >> 19;
      const int r = c & (CQ - 1);
      src = (t == 0) ? q : (t == 1) ? k : v;
      dst = (t == 0) ? qb : (t == 1) ? kb : vb;
      off = r << 3;
    } else {
      const int c2 = c - 3 * CQ;
      const int t = c2 >> 15;
      const int r = c2 & (CW - 1);
      src = (t == 0) ? Wq : (t == 1) ? Wk : (t == 2) ? Wv : Wo;
      dst = (t == 0) ? wq : (t == 1) ? wk : (t == 2) ? wv : wo;
      off = r << 3;
    }
    const float4 a = *(const float4*)(src + off);
    const float4 b = *(const float4*)(src + off + 4);
    *(bf16x8*)(dst + off) = cvt2(a, b);
  }
}

// ---------------------------------------------------------------------------
// qkv_proj: all three projections in ONE dispatch, bf16 in (R13-verified).
// Q/K epilogue: 128B-run coalesced stores.
// ---------------------------------------------------------------------------
__global__ void __launch_bounds__(256, 3)
qkv_proj(const bf16_t* __restrict__ qb, const bf16_t* __restrict__ kb,
         const bf16_t* __restrict__ vb,
         const bf16_t* __restrict__ Wqb, const float* __restrict__ bq,
         const bf16_t* __restrict__ Wkb, const float* __restrict__ bk,
         const bf16_t* __restrict__ Wvb, const float* __restrict__ bv,
         bf16_t* __restrict__ Qp, bf16_t* __restrict__ Kp,
         bf16_t* __restrict__ Vt, float qscale)
{
  __shared__ __align__(16) bf16_t S[2 * 128 * 72];   // As | Bs, 36,864 B
  bf16_t* As = S;
  bf16_t* Bs = S + 128 * 72;

  const int l     = blockIdx.x;                  // 0..767
  const int slice = l >> 8;                      // 0=Q, 1=K, 2=V
  const int inner = l & 255;
  const int mtile = ((inner & 7) << 3) | (inner >> 5);  // 0..63, XCD-contig
  const int ntile = (inner >> 3) & 3;                   // 0..3
  const int tid   = threadIdx.x;
  const int w     = tid >> 6;
  const int lane  = tid & 63;
  const int lr    = lane & 15;
  const int quad  = lane >> 4;
  const int wm    = w & 1;
  const int wn    = w >> 1;
  const int xrow  = tid >> 1, xcol = (tid & 1) << 5;  // stage: 128 rows x 64 cols

  const bf16_t* Xb   = (slice == 0) ? qb  : (slice == 1) ? kb  : vb;
  const bf16_t* W    = (slice == 0) ? Wqb : (slice == 1) ? Wkb : Wvb;
  const float*  bias = (slice == 0) ? bq  : (slice == 1) ? bk  : bv;
  const float scale  = (slice == 0) ? qscale : 1.0f;

  float bvv[4];
#pragma unroll
  for (int ci = 0; ci < 4; ++ci) bvv[ci] = bias[ntile * 128 + wn * 64 + ci * 16 + lr];

  f32x4 acc[4][4] = {};
  bf16x8 xa[4], wa[4];

#pragma unroll
  for (int j = 0; j < 4; ++j) {
    xa[j] = *(const bf16x8*)(Xb + (size_t)(mtile * 128 + xrow) * 512 + xcol + j * 8);
    wa[j] = *(const bf16x8*)(W  + (size_t)(ntile * 128 + xrow) * 512 + xcol + j * 8);
  }
#pragma unroll
  for (int j = 0; j < 4; ++j) {
    *(bf16x8*)(&As[xrow * 72 + xcol + j * 8]) = xa[j];
    *(bf16x8*)(&Bs[xrow * 72 + xcol + j * 8]) = wa[j];
  }
  __syncthreads();

  for (int it = 0; it < 8; ++it) {
    if (it != 7) {
      const int k0 = (it + 1) << 6;
#pragma unroll
      for (int j = 0; j < 4; ++j) {
        xa[j] = *(const bf16x8*)(Xb + (size_t)(mtile * 128 + xrow) * 512 + k0 + xcol + j * 8);
        wa[j] = *(const bf16x8*)(W  + (size_t)(ntile * 128 + xrow) * 512 + k0 + xcol + j * 8);
      }
    }
    bf16x8 af[4][2], bfr[4][2];
#pragma unroll
    for (int mi = 0; mi < 4; ++mi)
#pragma unroll
      for (int kh = 0; kh < 2; ++kh)
        af[mi][kh] = *(const bf16x8*)(&As[(wm * 64 + mi * 16 + lr) * 72 + (kh * 4 + quad) * 8]);
#pragma unroll
    for (int ci = 0; ci < 4; ++ci)
#pragma unroll
      for (int kh = 0; kh < 2; ++kh)
        bfr[ci][kh] = *(const bf16x8*)(&Bs[(wn * 64 + ci * 16 + lr) * 72 + (kh * 4 + quad) * 8]);
#pragma unroll
    for (int mi = 0; mi < 4; ++mi)
#pragma unroll
      for (int ci = 0; ci < 4; ++ci) {
        acc[mi][ci] = MFMA_BF16(af[mi][0], bfr[ci][0], acc[mi][ci], 0, 0, 0);
        acc[mi][ci] = MFMA_BF16(af[mi][1], bfr[ci][1], acc[mi][ci], 0, 0, 0);
      }
    __syncthreads();
    if (it != 7) {
#pragma unroll
      for (int j = 0; j < 4; ++j) {
        *(bf16x8*)(&As[xrow * 72 + xcol + j * 8]) = xa[j];
        *(bf16x8*)(&Bs[xrow * 72 + xcol + j * 8]) = wa[j];
      }
      __syncthreads();
    }
  }

  // ---- epilogue: LDS-staged coalesced stores ----
  bf16_t (*Ct)[136] = (bf16_t (*)[136])S;   // 128x136 bf16
  if (slice < 2) {
    bf16_t* outQK = (slice == 0) ? Qp : Kp;
#pragma unroll
    for (int mi = 0; mi < 4; ++mi)
#pragma unroll
      for (int ci = 0; ci < 4; ++ci)
#pragma unroll
        for (int r = 0; r < 4; ++r)
          Ct[wm * 64 + mi * 16 + quad * 4 + r][wn * 64 + ci * 16 + lr] =
              (bf16_t)((acc[mi][ci][r] + bvv[ci]) * scale);
    __syncthreads();
    // 256 runs of 128B: run R -> row=R>>1, h-half=R&1. 8 lanes per run.
    const int j8 = lane >> 3, slot = lane & 7;
#pragma unroll
    for (int p = 0; p < 8; ++p) {
      const int R = p * 32 + w * 8 + j8;       // 0..255, bijective
      const int row = R >> 1, colHalf = R & 1;
      const int gm = mtile * 128 + row;
      const int b = gm >> 12, n = gm & 4095;
      const int h = ntile * 2 + colHalf;
      *(bf16x8*)(outQK + (size_t)((b * 8 + h) * 4096 + n) * 64 + slot * 8) =
          *(const bf16x8*)(&Ct[row][colHalf * 64 + slot * 8]);
    }
  } else {
    // V: transpose in LDS -> Vt[B,H,D,N] rows of contiguous n
#pragma unroll
    for (int mi = 0; mi < 4; ++mi)
#pragma unroll
      for (int ci = 0; ci < 4; ++ci)
#pragma unroll
        for (int r = 0; r < 4; ++r)
          Ct[wn * 64 + ci * 16 + lr][wm * 64 + mi * 16 + quad * 4 + r] =
              (bf16_t)(acc[mi][ci][r] + bvv[ci]);
    __syncthreads();
    const int dline = tid >> 1, half = tid & 1;
    const int gc = ntile * 128 + dline;
    const int h = gc >> 6, dd = gc & 63;
    const int b = (mtile * 128) >> 12;
    const int n0 = (mtile * 128) & 4095;
    bf16_t* dst = Vt + (size_t)((b * 8 + h) * 64 + dd) * 4096 + n0 + half * 64;
#pragma unroll
    for (int j = 0; j < 8; ++j)
      *(bf16x8*)(dst + j * 8) = *(const bf16x8*)(&Ct[dline][half * 64 + j * 8]);
  }
}

// ---------------------------------------------------------------------------
// o_proj: final projection, f32 out [B,N,E]. 64x64 tile, grid 1024, 4/CU.
// NEW: LDS-staged epilogue — stage C (bias added) in Cf[64][68] f32, then
// 4 float4 passes/thread -> each instruction writes 4x256B contiguous runs
// (was 16 instrs x 4x64B segments).
// ---------------------------------------------------------------------------
__global__ void __launch_bounds__(256, 4)
o_proj(const bf16_t* __restrict__ Xb, const bf16_t* __restrict__ W,
       const float* __restrict__ bias, float* __restrict__ out)
{
  __shared__ __align__(16) bf16_t As[64 * 72];
  __shared__ __align__(16) bf16_t Bs[64 * 72];
  __shared__ __align__(16) float  Cf[64 * 68];   // 17,408 B; total 35,840 B
  const int l     = blockIdx.x;
  const int mtile = ((l & 7) << 4) | ((l >> 3) & 15);  // 0..127, XCD-contig
  const int ntile = l >> 7;                            // 0..7
  const int tid   = threadIdx.x;
  const int w     = tid >> 6;
  const int lane  = tid & 63;
  const int lr    = lane & 15;
  const int quad  = lane >> 4;
  const int wm    = w & 1;
  const int wn    = w >> 1;
  const int xrow  = tid >> 2, xcol = (tid & 3) << 4;  // 64 rows x 64 cols

  float bvv[2];
#pragma unroll
  for (int ci = 0; ci < 2; ++ci) bvv[ci] = bias[ntile * 64 + wn * 32 + ci * 16 + lr];

  f32x4 acc[2][2] = {};
  bf16x8 xb[2], wb[2];

#pragma unroll
  for (int j = 0; j < 2; ++j) {
    xb[j] = *(const bf16x8*)(Xb + (size_t)(mtile * 64 + xrow) * 512 + xcol + j * 8);
    wb[j] = *(const bf16x8*)(W  + (size_t)(ntile * 64 + xrow) * 512 + xcol + j * 8);
  }
#pragma unroll
  for (int j = 0; j < 2; ++j) {
    *(bf16x8*)(&As[xrow * 72 + xcol + j * 8]) = xb[j];
    *(bf16x8*)(&Bs[xrow * 72 + xcol + j * 8]) = wb[j];
  }
  __syncthreads();

  for (int it = 0; it < 8; ++it) {
    if (it != 7) {
      const int k0 = (it + 1) << 6;
#pragma unroll
      for (int j = 0; j < 2; ++j) {
        xb[j] = *(const bf16x8*)(Xb + (size_t)(mtile * 64 + xrow) * 512 + k0 + xcol + j * 8);
        wb[j] = *(const bf16x8*)(W  + (size_t)(ntile * 64 + xrow) * 512 + k0 + xcol + j * 8);
      }
    }
    bf16x8 af[2][2], bfr[2][2];
#pragma unroll
    for (int mi = 0; mi < 2; ++mi)
#pragma unroll
      for (int kh = 0; kh < 2; ++kh)
        af[mi][kh] = *(const bf16x8*)(&As[(wm * 32 + mi * 16 + lr) * 72 + (kh * 4 + quad) * 8]);
#pragma unroll
    for (int ci = 0; ci < 2; ++ci)
#pragma unroll
      for (int kh = 0; kh < 2; ++kh)
        bfr[ci][kh] = *(const bf16x8*)(&Bs[(wn * 32 + ci * 16 + lr) * 72 + (kh * 4 + quad) * 8]);
#pragma unroll
    for (int mi = 0; mi < 2; ++mi)
#pragma unroll
      for (int ci = 0; ci < 2; ++ci) {
        acc[mi][ci] = MFMA_BF16(af[mi][0], bfr[ci][0], acc[mi][ci], 0, 0, 0);
        acc[mi][ci] = MFMA_BF16(af[mi][1], bfr[ci][1], acc[mi][ci], 0, 0, 0);
      }
    __syncthreads();
    if (it != 7) {
#pragma unroll
      for (int j = 0; j < 2; ++j) {
        *(bf16x8*)(&As[xrow * 72 + xcol + j * 8]) = xb[j];
        *(bf16x8*)(&Bs[xrow * 72 + xcol + j * 8]) = wb[j];
      }
      __syncthreads();
    }
  }

  // ---- epilogue: stage C (with bias) in LDS, then 256B-run stores ----
#pragma unroll
  for (int mi = 0; mi < 2; ++mi)
#pragma unroll
    for (int ci = 0; ci < 2; ++ci)
#pragma unroll
      for (int r = 0; r < 4; ++r)
        Cf[(wm * 32 + mi * 16 + quad * 4 + r) * 68 + (wn * 32 + ci * 16 + lr)] =
            acc[mi][ci][r] + bvv[ci];
  __syncthreads();
#pragma unroll
  for (int p = 0; p < 4; ++p) {
    const int idx = p * 256 + tid;        // 0..1023
    const int row = idx >> 4, c4 = idx & 15;
    const float4 v = *(const float4*)(&Cf[row * 68 + c4 * 4]);
    *(float4*)(out + (size_t)(mtile * 64 + row) * 512 + ntile * 64 + c4 * 4) = v;
  }
}

// ---------------------------------------------------------------------------
// flash_attn v16 (R11/R13-verified, 83-84us): 512 thr = 8 waves, grid (16,32),
// 2 blocks/CU -> 16 waves/CU. Group g = wave>>2: g0 = KV chunks 0..31,
// g1 = 32..63; private dbuf K/V LDS per group (73,728 B). 32 q-rows/wave,
// transposed S, m=0 softmax, in-register P exchange. Padded f32 merge
// (stride 33/3). No setprio.
// ---------------------------------------------------------------------------
__global__ void __launch_bounds__(512, 2)
flash_attn(const bf16_t* __restrict__ Qp, const bf16_t* __restrict__ Kp,
           const bf16_t* __restrict__ Vt, bf16_t* __restrict__ Oc)
{
  __shared__ __align__(16) bf16_t Klds[2][2][64 * 72];   // [g][buf]
  __shared__ __align__(16) bf16_t Vlds[2][2][64 * 72];

  const int tid  = threadIdx.x;
  const int w    = tid >> 6;               // 0..7
  const int g    = w >> 2;                 // 0..1  (KV half)
  const int wl   = w & 3;                  // 0..3  (q sub-tile)
  const int lane = tid & 63, lr = lane & 15, quad = lane >> 4;
  const int bh   = blockIdx.x;
  const int qt0  = blockIdx.y * 128 + wl * 32;

  const bf16_t* Qh = Qp + (size_t)bh * 4096 * 64;
  const bf16_t* Kh = Kp + (size_t)bh * 4096 * 64;
  const bf16_t* Vh = Vt + (size_t)bh * 64 * 4096;

  const int tg   = tid & 255;              // thread-in-group
  const int srow = tg >> 2;                // 0..63
  const int scol = (tg & 3) << 4;          // 0,16,32,48
  const int kvbase = g << 11;              // g*32 chunks * 64 rows

  bf16x8 qf[2][2];
#pragma unroll
  for (int qi = 0; qi < 2; ++qi)
#pragma unroll
    for (int kh = 0; kh < 2; ++kh)
      qf[qi][kh] = *(const bf16x8*)(Qh + (size_t)(qt0 + qi * 16 + lr) * 64 + kh * 32 + quad * 8);

  bf16x8 kst[2], vst[2];
#pragma unroll
  for (int j = 0; j < 2; ++j) {
    kst[j] = *(const bf16x8*)(Kh + (size_t)(kvbase + srow) * 64 + scol + j * 8);
    vst[j] = *(const bf16x8*)(Vh + (size_t)srow * 4096 + kvbase + scol + j * 8);
  }
#pragma unroll
  for (int j = 0; j < 2; ++j) {
    *(bf16x8*)(&Klds[g][0][srow * 72 + scol + j * 8]) = kst[j];
    *(bf16x8*)(&Vlds[g][0][srow * 72 + scol + j * 8]) = vst[j];
  }
  __syncthreads();

  f32x4 acc[2][4] = {};
  float lsum[2] = {0.f, 0.f};
  const f32x4 zero = {0.f, 0.f, 0.f, 0.f};

  for (int it = 0; it < 32; ++it) {
    const int cur = it & 1, nxt = cur ^ 1;

    if (it != 31) {
      const int kvn = kvbase + ((it + 1) << 6);
#pragma unroll
      for (int j = 0; j < 2; ++j) {
        kst[j] = *(const bf16x8*)(Kh + (size_t)(kvn + srow) * 64 + scol + j * 8);
        vst[j] = *(const bf16x8*)(Vh + (size_t)srow * 4096 + kvn + scol + j * 8);
      }
    }

    bf16x8 kf[4][2];
#pragma unroll
    for (int mt = 0; mt < 4; ++mt)
#pragma unroll
      for (int kh = 0; kh < 2; ++kh)
        kf[mt][kh] = *(const bf16x8*)(&Klds[g][cur][(mt * 16 + lr) * 72 + (kh * 4 + quad) * 8]);
    bf16x8 vf[4][2];
#pragma unroll
    for (int t = 0; t < 4; ++t)
#pragma unroll
      for (int kvh = 0; kvh < 2; ++kvh)
        vf[t][kvh] = *(const bf16x8*)(&Vlds[g][cur][(t * 16 + lr) * 72 + (kvh * 4 + quad) * 8]);

    f32x4 sT[4][2];
#pragma unroll
    for (int mt = 0; mt < 4; ++mt)
#pragma unroll
      for (int qi = 0; qi < 2; ++qi) {
        sT[mt][qi] = MFMA_BF16(kf[mt][0], qf[qi][0], zero, 0, 0, 0);
        sT[mt][qi] = MFMA_BF16(kf[mt][1], qf[qi][1], sT[mt][qi], 0, 0, 0);
      }

    // softmax + in-register P exchange (S^T C-layout -> PV A-frag layout)
    bf16x8 pa[2][2];
#pragma unroll
    for (int qi = 0; qi < 2; ++qi) {
      uint32_t ap[4], bp[4];
#pragma unroll
      for (int mt = 0; mt < 4; ++mt) {
        float p0 = __builtin_amdgcn_exp2f(sT[mt][qi][0]);
        float p1 = __builtin_amdgcn_exp2f(sT[mt][qi][1]);
        float p2 = __builtin_amdgcn_exp2f(sT[mt][qi][2]);
        float p3 = __builtin_amdgcn_exp2f(sT[mt][qi][3]);
        lsum[qi] += (p0 + p1) + (p2 + p3);
        ap[mt] = pk2(p0, p1);
        bp[mt] = pk2(p2, p3);
      }
#pragma unroll
      for (int kvh = 0; kvh < 2; ++kvh) {
        uint32_t xa_ = ap[2 * kvh], ya_ = ap[2 * kvh + 1];
        asm("v_permlane32_swap_b32 %0, %1" : "+v"(xa_), "+v"(ya_));
        asm("v_permlane16_swap_b32 %0, %1" : "+v"(xa_), "+v"(ya_));
        uint32_t xb_ = bp[2 * kvh], yb_ = bp[2 * kvh + 1];
        asm("v_permlane32_swap_b32 %0, %1" : "+v"(xb_), "+v"(yb_));
        asm("v_permlane16_swap_b32 %0, %1" : "+v"(xb_), "+v"(yb_));
        union { uint32_t u[4]; bf16x8 v; } pu;
        pu.u[0] = xa_; pu.u[1] = xb_; pu.u[2] = ya_; pu.u[3] = yb_;
        pa[qi][kvh] = pu.v;
      }
    }

#pragma unroll
    for (int t = 0; t < 4; ++t)
#pragma unroll
      for (int qi = 0; qi < 2; ++qi) {
        acc[qi][t] = MFMA_BF16(pa[qi][0], vf[t][0], acc[qi][t], 0, 0, 0);
        acc[qi][t] = MFMA_BF16(pa[qi][1], vf[t][1], acc[qi][t], 0, 0, 0);
      }

    if (it != 31) {
#pragma unroll
      for (int j = 0; j < 2; ++j) {
        *(bf16x8*)(&Klds[g][nxt][srow * 72 + scol + j * 8]) = kst[j];
        *(bf16x8*)(&Vlds[g][nxt][srow * 72 + scol + j * 8]) = vst[j];
      }
    }
    __syncthreads();
  }

  // intra-wave reduce lsum across quads (each lane ends with its lr-row sum)
#pragma unroll
  for (int qi = 0; qi < 2; ++qi) {
    lsum[qi] += __shfl_xor(lsum[qi], 16);
    lsum[qi] += __shfl_xor(lsum[qi], 32);
  }

  // ---- merge g1 -> g0 via LDS (K staging is dead; padded strides) ----
  float* accM  = (float*)&Klds[0][0][0];
  float* lsumM = accM + 4 * 64 * 33;
  const int mslot = (wl * 64 + lane);
  if (g == 1) {
#pragma unroll
    for (int qi = 0; qi < 2; ++qi) {
      lsumM[mslot * 3 + qi] = lsum[qi];
#pragma unroll
      for (int t = 0; t < 4; ++t)
#pragma unroll
        for (int r = 0; r < 4; ++r)
          accM[mslot * 33 + qi * 16 + t * 4 + r] = acc[qi][t][r];
    }
  }
  __syncthreads();
  if (g == 1) return;

#pragma unroll
  for (int qi = 0; qi < 2; ++qi) {
    lsum[qi] += lsumM[mslot * 3 + qi];
#pragma unroll
    for (int t = 0; t < 4; ++t)
#pragma unroll
      for (int r = 0; r < 4; ++r)
        acc[qi][t][r] += accM[mslot * 33 + qi * 16 + t * 4 + r];
  }

  const int b = bh >> 3, h = bh & 7;
  bf16_t* Ob = Oc + (size_t)b * 4096 * 512 + h * 64;
#pragma unroll
  for (int qi = 0; qi < 2; ++qi) {
    float inv[4];
#pragma unroll
    for (int r = 0; r < 4; ++r)
      inv[r] = 1.0f / __shfl(lsum[qi], quad * 4 + r);
#pragma unroll
    for (int t = 0; t < 4; ++t)
#pragma unroll
      for (int r = 0; r < 4; ++r) {
        const int n = qt0 + qi * 16 + quad * 4 + r;
        Ob[(size_t)n * 512 + t * 16 + lr] = (bf16_t)(acc[qi][t][r] * inv[r]);
      }
  }
}

// ---------------------------------------------------------------------------
extern "C" void kernel_launch(void* const* d_in, const int* in_sizes, int n_in,
                              void* d_out, int out_size, void* d_ws, size_t ws_size,
                              hipStream_t stream)
{
  const float* q  = (const float*)d_in[0];
  const float* k  = (const float*)d_in[1];
  const float* v  = (const float*)d_in[2];
  const float* Wq = (const float*)d_in[3];
  const float* bq = (const float*)d_in[4];
  const float* Wk = (const float*)d_in[5];
  const float* bk = (const float*)d_in[6];
  const float* Wv = (const float*)d_in[7];
  const float* bv = (const float*)d_in[8];
  const float* Wo = (const float*)d_in[9];
  const float* bo = (const float*)d_in[10];

  const size_t HEAD_ELEMS = (size_t)2 * 8 * 4096 * 64;  // 4,194,304 (8 MB bf16)
  const size_t W_ELEMS    = (size_t)512 * 512;          // 262,144

  bf16_t* base = (bf16_t*)d_ws;
  bf16_t* qb  = base;                        // [B,N,E] bf16
  bf16_t* kb  = qb + HEAD_ELEMS;
  bf16_t* vb  = kb + HEAD_ELEMS;
  bf16_t* Qp  = vb + HEAD_ELEMS;             // [B,H,N,D], pre-scaled
  bf16_t* Kp  = Qp + HEAD_ELEMS;             // [B,H,N,D]
  bf16_t* Vt  = Kp + HEAD_ELEMS;             // [B,H,D,N]
  bf16_t* wqb = Vt + HEAD_ELEMS;
  bf16_t* wkb = wqb + W_ELEMS;
  bf16_t* wvb = wkb + W_ELEMS;
  bf16_t* wob = wvb + W_ELEMS;
  bf16_t* Oc  = qb;   // aliases qb: dead after qkv_proj, Oc written by flash

  const float qscale = 0.125f * 1.44269504f;  // 1/sqrt(D) * log2(e)

  cvt_bf16<<<dim3(2048), 256, 0, stream>>>(q, k, v, Wq, Wk, Wv, Wo,
                                           qb, kb, vb, wqb, wkb, wvb, wob);
  qkv_proj<<<dim3(768), 256, 0, stream>>>(qb, kb, vb, wqb, bq, wkb, bk,
                                          wvb, bv, Qp, Kp, Vt, qscale);
  flash_attn<<<dim3(16, 32), 512, 0, stream>>>(Qp, Kp, Vt, Oc);
  o_proj<<<dim3(1024), 256, 0, stream>>>(Oc, wob, bo, (float*)d_out);
}